// Round 3
// baseline (238.969 us; speedup 1.0000x reference)
//
#include <hip/hip_runtime.h>
#include <hip/hip_fp16.h>

typedef _Float16 f16;
typedef _Float16 f16x8 __attribute__((ext_vector_type(8)));
typedef _Float16 f16x2v __attribute__((ext_vector_type(2)));
typedef __fp16 h16x2 __attribute__((ext_vector_type(2)));
typedef float f32x4 __attribute__((ext_vector_type(4)));
typedef float f32x16 __attribute__((ext_vector_type(16)));

#define LOG2E 1.4426950408889634f
#define NSL 0.2f

// ---------------- Kernel A: xcvt + swizzled weight transposes + M2e init ----------------
__global__ __launch_bounds__(256) void k_a(const float* __restrict__ x,
                                           f16* __restrict__ xh2,
                                           const float* __restrict__ W,
                                           f16* __restrict__ Wht2,
                                           const float* __restrict__ Wr,
                                           f16* __restrict__ Wrt2,
                                           unsigned int* __restrict__ M2e) {
    __shared__ float tile[32][33];
    int bx = blockIdx.x;
    int tid = threadIdx.x;
    if (bx == 0 && tid < 8) M2e[tid] = 0x007FFFFFu;  // enc(-inf)
    if (bx < 512) {
        int id = bx * 256 + tid;   // 131072
        int row = id & 4095, kt = id >> 12;
        const float4* xs = (const float4*)(x + (size_t)row * 512 + kt * 16);
        float4 u0 = xs[0], u1 = xs[1], u2 = xs[2], u3 = xs[3];
        union { int4 a[2]; h16x2 p[8]; } px;
        px.p[0] = __builtin_amdgcn_cvt_pkrtz(u0.x, u0.y);
        px.p[1] = __builtin_amdgcn_cvt_pkrtz(u0.z, u0.w);
        px.p[2] = __builtin_amdgcn_cvt_pkrtz(u1.x, u1.y);
        px.p[3] = __builtin_amdgcn_cvt_pkrtz(u1.z, u1.w);
        px.p[4] = __builtin_amdgcn_cvt_pkrtz(u2.x, u2.y);
        px.p[5] = __builtin_amdgcn_cvt_pkrtz(u2.z, u2.w);
        px.p[6] = __builtin_amdgcn_cvt_pkrtz(u3.x, u3.y);
        px.p[7] = __builtin_amdgcn_cvt_pkrtz(u3.z, u3.w);
        int4* d = (int4*)(xh2 + ((size_t)kt * 4096 + row) * 16);
        d[0] = px.a[0]; d[1] = px.a[1];
    } else {
        const float* in; f16* out; int C, S, bxx, byy;
        if (bx < 1024) { int id = bx - 512;  in = W;  out = Wht2; C = 128;  S = 128;  bxx = id & 3;  byy = id >> 2; }
        else           { int id = bx - 1024; in = Wr; out = Wrt2; C = 1024; S = 1024; bxx = id & 31; byy = id >> 5; }
        int tx = tid & 31, ty = tid >> 5;
        int c0 = bxx * 32, r0 = byy * 32;
        for (int rr = ty; rr < 32; rr += 8)
            tile[rr][tx] = in[(r0 + rr) * C + c0 + tx];
        __syncthreads();
        for (int rr = ty; rr < 32; rr += 8) {
            int m = r0 + tx, f = c0 + rr;
            out[(size_t)((m >> 4) * S + f) * 16 + (m & 15)] = (f16)tile[tx][rr];
        }
    }
}

// ---------------- Kernel B (fused): gemm_h (blocks 0..1023) + graph bitmask (1024..2047) ----------------
__global__ __launch_bounds__(256, 4) void k_b(const f16* __restrict__ xh2,
                                              const f16* __restrict__ Wht2,
                                              f16* __restrict__ hbT2,
                                              const float* __restrict__ wi,
                                              const float* __restrict__ wj,
                                              float* __restrict__ a2,
                                              float* __restrict__ b2,
                                              unsigned int* __restrict__ M2e,
                                              const int* __restrict__ graph,
                                              unsigned int* __restrict__ maskJ) {
    __shared__ float swi[128], swj[128];
    __shared__ float pwa[4][32], pwb[4][32];
    __shared__ unsigned long long bal[4][64];
    int bx = blockIdx.x;
    int tid = threadIdx.x;
    int w = tid >> 6, lane = tid & 63;

    if (bx >= 1024) {
        // ---- mask part ----
        int gw = (bx - 1024) * 4 + w;
        int ti = gw & 63, tj = gw >> 6;
        int i0 = ti * 64, j0 = tj * 64;
        #pragma unroll 8
        for (int k = 0; k < 64; k++) {
            int g = graph[(j0 + k) * 4096 + i0 + lane];
            unsigned long long b = __ballot(g > 0);
            if (lane == 0) bal[w][k] = b;
        }
        __syncthreads();
        unsigned long long word = 0;
        #pragma unroll 8
        for (int k = 0; k < 64; k++) {
            word |= ((bal[w][k] >> lane) & 1ull) << k;
        }
        int jw = j0 >> 5;
        maskJ[(size_t)jw * 4096 + i0 + lane]       = (unsigned int)word;
        maskJ[(size_t)(jw + 1) * 4096 + i0 + lane] = (unsigned int)(word >> 32);
        return;
    }

    // ---- gemm part ----
    int h = bx & 7, jb = bx >> 3;        // 128 j-tiles of 32
    int j0 = jb * 32;
    int ln = lane & 15, q = lane >> 4;
    if (tid < 128) { swi[tid] = wi[h * 128 + tid]; swj[tid] = wj[h * 128 + tid]; }
    __syncthreads();

    int ko = (q & 1) * 8;
    const f16* pa = Wht2 + ((size_t)(h * 512) * 8 + (size_t)(q >> 1) * 128 + w * 32 + ln) * 16 + ko;
    const f16* pb = xh2 + ((size_t)(q >> 1) * 4096 + j0 + ln) * 16 + ko;

    f32x4 acc00 = {}, acc01 = {}, acc10 = {}, acc11 = {};

    f16x8 ra0 = *(const f16x8*)(pa);
    f16x8 ra1 = *(const f16x8*)(pa + 256);
    f16x8 rb0 = *(const f16x8*)(pb);
    f16x8 rb1 = *(const f16x8*)(pb + 256);

    for (int kk = 0; kk < 8; kk++) {
        f16x8 sa0 = *(const f16x8*)(pa + 4096);
        f16x8 sa1 = *(const f16x8*)(pa + 4096 + 256);
        f16x8 sb0 = *(const f16x8*)(pb + 131072);
        f16x8 sb1 = *(const f16x8*)(pb + 131072 + 256);
        acc00 = __builtin_amdgcn_mfma_f32_16x16x32_f16(ra0, rb0, acc00, 0, 0, 0);
        acc01 = __builtin_amdgcn_mfma_f32_16x16x32_f16(ra0, rb1, acc01, 0, 0, 0);
        acc10 = __builtin_amdgcn_mfma_f32_16x16x32_f16(ra1, rb0, acc10, 0, 0, 0);
        acc11 = __builtin_amdgcn_mfma_f32_16x16x32_f16(ra1, rb1, acc11, 0, 0, 0);
        pa += 8192; pb += 262144;
        ra0 = *(const f16x8*)(pa);
        ra1 = *(const f16x8*)(pa + 256);
        rb0 = *(const f16x8*)(pb);
        rb1 = *(const f16x8*)(pb + 256);
        acc00 = __builtin_amdgcn_mfma_f32_16x16x32_f16(sa0, sb0, acc00, 0, 0, 0);
        acc01 = __builtin_amdgcn_mfma_f32_16x16x32_f16(sa0, sb1, acc01, 0, 0, 0);
        acc10 = __builtin_amdgcn_mfma_f32_16x16x32_f16(sa1, sb0, acc10, 0, 0, 0);
        acc11 = __builtin_amdgcn_mfma_f32_16x16x32_f16(sa1, sb1, acc11, 0, 0, 0);
    }

    size_t hb = (size_t)h * 524288 + (size_t)(j0 >> 4) * 2048;
    #pragma unroll
    for (int r = 0; r < 4; r++) {
        int f0 = w * 32 + q * 4 + r;
        hbT2[hb + f0 * 16 + ln]                 = (f16)acc00[r];
        hbT2[hb + 2048 + f0 * 16 + ln]          = (f16)acc01[r];
        hbT2[hb + (f0 + 16) * 16 + ln]          = (f16)acc10[r];
        hbT2[hb + 2048 + (f0 + 16) * 16 + ln]   = (f16)acc11[r];
    }

    float pa0 = 0.f, pb0 = 0.f, pa1 = 0.f, pb1 = 0.f;
    #pragma unroll
    for (int r = 0; r < 4; r++) {
        int f0 = w * 32 + q * 4 + r;
        float w0 = swi[f0], jv0 = swj[f0];
        float w1 = swi[f0 + 16], jv1 = swj[f0 + 16];
        pa0 += acc00[r] * w0 + acc10[r] * w1;
        pb0 += acc00[r] * jv0 + acc10[r] * jv1;
        pa1 += acc01[r] * w0 + acc11[r] * w1;
        pb1 += acc01[r] * jv0 + acc11[r] * jv1;
    }
    pa0 += __shfl_xor(pa0, 16); pa0 += __shfl_xor(pa0, 32);
    pb0 += __shfl_xor(pb0, 16); pb0 += __shfl_xor(pb0, 32);
    pa1 += __shfl_xor(pa1, 16); pa1 += __shfl_xor(pa1, 32);
    pb1 += __shfl_xor(pb1, 16); pb1 += __shfl_xor(pb1, 32);
    if (lane < 16) {
        pwa[w][ln] = pa0;      pwb[w][ln] = pb0;
        pwa[w][16 + ln] = pa1; pwb[w][16 + ln] = pb1;
    }
    __syncthreads();
    if (tid < 32) {
        int jj = tid;
        float pav = (pwa[0][jj] + pwa[1][jj]) + (pwa[2][jj] + pwa[3][jj]);
        float pbv = (pwb[0][jj] + pwb[1][jj]) + (pwb[2][jj] + pwb[3][jj]);
        a2[h * 4096 + j0 + jj] = pav * LOG2E;
        float bb = pbv * LOG2E;
        b2[h * 4096 + j0 + jj] = bb;
        float m = bb;
        m = fmaxf(m, __shfl_xor(m, 1, 32));
        m = fmaxf(m, __shfl_xor(m, 2, 32));
        m = fmaxf(m, __shfl_xor(m, 4, 32));
        m = fmaxf(m, __shfl_xor(m, 8, 32));
        m = fmaxf(m, __shfl_xor(m, 16, 32));
        if (jj == 0) {
            unsigned u = __float_as_uint(m);
            unsigned enc = (u & 0x80000000u) ? ~u : (u | 0x80000000u);
            atomicMax(&M2e[h], enc);
        }
    }
}

// ---------------- Kernel 6 helpers ----------------
#define PGEN2(af, m8, qv, qw)                                                        \
    {                                                                                \
        union { int4 i4; unsigned u[4]; } uv, uw;                                    \
        uv.i4 = (qv); uw.i4 = (qw);                                                  \
        f16x2v dl = {(_Float16)0, (_Float16)0};                                      \
        _Pragma("unroll")                                                            \
        for (int p = 0; p < 4; p++) {                                                \
            union { unsigned u; f16x2v v; } b1, b2x, mm;                             \
            b1.u = uv.u[p]; b2x.u = uw.u[p];                                         \
            f16x2v pr1 = Ap1 * b1.v;                                                 \
            f16x2v pr2 = Ap2 * b2x.v;                                                \
            mm.v = __builtin_elementwise_max(pr1, pr2);                              \
            int mlo = -(int)(((m8) >> (2 * p)) & 1u);                                \
            int mhi = -(int)(((m8) >> (2 * p + 1)) & 1u);                            \
            unsigned comb = ((unsigned)mlo & 0xFFFFu) | ((unsigned)mhi & 0xFFFF0000u);\
            mm.u &= comb;                                                            \
            af.u[p] = mm.u;                                                          \
            dl += mm.v;                                                              \
        }                                                                            \
        dsum += (float)dl.x + (float)dl.y;                                           \
    }

#define PUTACC(dp, off, accv)                                                    \
    {                                                                            \
        union { f32x16 v; f32x4 q[4]; } t; t.v = (accv);                         \
        *(f32x4*)((dp) + (off))      = t.q[0];                                   \
        *(f32x4*)((dp) + (off) + 4)  = t.q[1];                                   \
        *(f32x4*)((dp) + (off) + 8)  = t.q[2];                                   \
        *(f32x4*)((dp) + (off) + 12) = t.q[3];                                   \
    }

#define ADDACC(dp, off, accv)                                                    \
    {                                                                            \
        union { f32x16 v; f32x4 q[4]; } t; t.v = (accv);                         \
        t.q[0] += *(const f32x4*)((dp) + (off));                                 \
        t.q[1] += *(const f32x4*)((dp) + (off) + 4);                             \
        t.q[2] += *(const f32x4*)((dp) + (off) + 8);                             \
        t.q[3] += *(const f32x4*)((dp) + (off) + 12);                            \
        (accv) = t.v;                                                            \
    }

// One half-phase of the main loop. TC = half-phase index (0..63).
// Computes with fragment set C*, loads fragment set L* for half-phase TC+2 (distance-2),
// loads qv/qw set for TC+1, and (if DOM) loads the mask word for pair (TC>>1)+2.
#define HPH(TC, C0, C1, C2, C3, L0, L1, L2, L3, QVC, QWC, QVL, QWL, MB, SH, DOM, MLD) \
    {                                                                                 \
        const f16* sl = bb + (size_t)((TC) + 2) * 2048;                               \
        L0 = *(const f16x8*)(sl);                                                     \
        L1 = *(const f16x8*)(sl + 512);                                               \
        L2 = *(const f16x8*)(sl + 1024);                                              \
        L3 = *(const f16x8*)(sl + 1536);                                              \
        QVL = *(const int4*)(bpv + ((TC) + 1) * 8);                                   \
        QWL = *(const int4*)(bpw + ((TC) + 1) * 8);                                   \
        if (DOM) { MLD = mrow[((TC) >> 1) + 2]; }                                     \
        union { f16x8 v; unsigned u[4]; } af;                                         \
        PGEN2(af, (MB) >> (SH), QVC, QWC);                                            \
        acc0 = __builtin_amdgcn_mfma_f32_32x32x16_f16(af.v, C0, acc0, 0, 0, 0);       \
        acc1 = __builtin_amdgcn_mfma_f32_32x32x16_f16(af.v, C1, acc1, 0, 0, 0);       \
        acc2 = __builtin_amdgcn_mfma_f32_32x32x16_f16(af.v, C2, acc2, 0, 0, 0);       \
        acc3 = __builtin_amdgcn_mfma_f32_32x32x16_f16(af.v, C3, acc3, 0, 0, 0);       \
    }

// ---------------- Kernel 6: main — distance-2 fragment pipeline (3-buffer rotation),
// in-kernel exp-table build, LDS-staged tables/mask, pk_max PGEN, 3 waves/SIMD ----------------
__global__ __launch_bounds__(256, 3) void k_main(const f16* __restrict__ xh2,
                                                 const f16* __restrict__ hbT2,
                                                 const f16* __restrict__ Wrt2,
                                                 const unsigned int* __restrict__ maskJ,
                                                 const float* __restrict__ a2,
                                                 const float* __restrict__ b2,
                                                 const unsigned int* __restrict__ M2e,
                                                 const float* __restrict__ bias,
                                                 float* __restrict__ out) {
    __shared__ char smem[35328];          // [0,16512) mask[32][129] | [16512,24704) Bv | [24704,32896) Bw
    __shared__ float dred[128];           // (all dead after loop; xred aliases [0,34816))

    unsigned int* mlds = (unsigned int*)smem;
    unsigned int* bvlds = (unsigned int*)(smem + 16512);
    unsigned int* bwlds = (unsigned int*)(smem + 24704);

    int bx = blockIdx.x;
    int h = bx & 7, it = bx >> 3;
    int i0 = it * 32;
    int tid = threadIdx.x;
    int w = tid >> 6, lane = tid & 63;
    int l31 = lane & 31, half = lane >> 5;
    int i = i0 + l31;

    unsigned enc = M2e[h];
    unsigned um = (enc & 0x80000000u) ? (enc & 0x7FFFFFFFu) : ~enc;
    float M2 = __uint_as_float(um);

    // ---- build Bv/Bw tables in LDS from b2 + stage mask strip ----
    {
        const float2* bsrc = (const float2*)(b2 + h * 4096);
        #pragma unroll
        for (int c = 0; c < 8; c++) {
            int p = tid + c * 256;                 // 2048 j-pairs
            float2 tb = bsrc[p];
            float t0 = tb.x - M2, t1 = tb.y - M2;
            union { h16x2 pp; unsigned ii; } k1, k2;
            k1.pp = __builtin_amdgcn_cvt_pkrtz(exp2f(t0), exp2f(t1));
            k2.pp = __builtin_amdgcn_cvt_pkrtz(exp2f(NSL * t0), exp2f(NSL * t1));
            bvlds[p] = k1.ii;
            bwlds[p] = k2.ii;
        }
        #pragma unroll
        for (int c = 0; c < 16; c++) {
            int e = tid + c * 256;                 // e = jw*32 + i
            int jw = e >> 5, ii = e & 31;
            mlds[ii * 129 + jw] = maskJ[(size_t)jw * 4096 + i0 + ii];
        }
    }

    // ---- per-row A factors ----
    float av = a2[h * 4096 + i];
    float uu = av + M2;
    float m2v = fmaxf(uu, NSL * uu);
    union { h16x2 pp; f16x2v v; } apk;
    apk.pp = __builtin_amdgcn_cvt_pkrtz(exp2f(uu - m2v), exp2f(NSL * uu - m2v));
    f16x2v Ap1 = {apk.v.x, apk.v.x};
    f16x2v Ap2 = {apk.v.y, apk.v.y};

    f32x16 acc0 = {}, acc1 = {}, acc2 = {}, acc3 = {};
    float dsum = 0.f;

    int J0 = w * 1024;
    const f16* bb = hbT2 + (size_t)h * 524288 + ((size_t)(J0 >> 4) * 128 + l31) * 16 + half * 8;
    const unsigned int* bpv = bvlds + (J0 >> 1) + half * 4;
    const unsigned int* bpw = bwlds + (J0 >> 1) + half * 4;
    const unsigned int* mrow = mlds + l31 * 129 + (J0 >> 5);

    int sh0 = half << 3;
    int sh1 = 16 + (half << 3);

    __syncthreads();

    // ---- prologue: fragment sets for half-phases 0 and 1; qv/qw for 0; mask pairs 0,1 ----
    f16x8 fA0 = *(const f16x8*)(bb);
    f16x8 fA1 = *(const f16x8*)(bb + 512);
    f16x8 fA2 = *(const f16x8*)(bb + 1024);
    f16x8 fA3 = *(const f16x8*)(bb + 1536);
    f16x8 fB0 = *(const f16x8*)(bb + 2048);
    f16x8 fB1 = *(const f16x8*)(bb + 2048 + 512);
    f16x8 fB2 = *(const f16x8*)(bb + 2048 + 1024);
    f16x8 fB3 = *(const f16x8*)(bb + 2048 + 1536);
    f16x8 fC0, fC1, fC2, fC3;
    int4 qva = ((const int4*)(bpv))[0];
    int4 qwa = ((const int4*)(bpw))[0];
    int4 qvb, qwb;
    unsigned m0 = mrow[0];
    unsigned m1 = mrow[1];
    unsigned m2w = 0;

    // ---- main loop: 64 half-phases, 6-unrolled for static buffer rotation ----
    #pragma unroll 1
    for (int tb = 0; tb < 60; tb += 6) {
        HPH(tb + 0, fA0, fA1, fA2, fA3, fC0, fC1, fC2, fC3, qva, qwa, qvb, qwb, m0, sh0, 1, m2w);
        HPH(tb + 1, fB0, fB1, fB2, fB3, fA0, fA1, fA2, fA3, qvb, qwb, qva, qwa, m0, sh1, 0, m2w);
        m0 = m1; m1 = m2w;
        HPH(tb + 2, fC0, fC1, fC2, fC3, fB0, fB1, fB2, fB3, qva, qwa, qvb, qwb, m0, sh0, 1, m2w);
        HPH(tb + 3, fA0, fA1, fA2, fA3, fC0, fC1, fC2, fC3, qvb, qwb, qva, qwa, m0, sh1, 0, m2w);
        m0 = m1; m1 = m2w;
        HPH(tb + 4, fB0, fB1, fB2, fB3, fA0, fA1, fA2, fA3, qva, qwa, qvb, qwb, m0, sh0, 1, m2w);
        HPH(tb + 5, fC0, fC1, fC2, fC3, fB0, fB1, fB2, fB3, qvb, qwb, qva, qwa, m0, sh1, 0, m2w);
        m0 = m1; m1 = m2w;
    }
    // ---- tail: half-phases 60..63 (loads at 62/63 overread into allocated ws/LDS; unused) ----
    HPH(60, fA0, fA1, fA2, fA3, fC0, fC1, fC2, fC3, qva, qwa, qvb, qwb, m0, sh0, 1, m2w);
    HPH(61, fB0, fB1, fB2, fB3, fA0, fA1, fA2, fA3, qvb, qwb, qva, qwa, m0, sh1, 0, m2w);
    m0 = m1; m1 = m2w;
    HPH(62, fC0, fC1, fC2, fC3, fB0, fB1, fB2, fB3, qva, qwa, qvb, qwb, m0, sh0, 0, m2w);
    HPH(63, fA0, fA1, fA2, fA3, fC0, fC1, fC2, fC3, qvb, qwb, qva, qwa, m0, sh1, 0, m2w);

    // ---- denominator ----
    dsum += __shfl(dsum, lane ^ 32);
    if (lane < 32) dred[w * 32 + l31] = dsum;
    __syncthreads();
    {
        #pragma unroll
        for (int r = 0; r < 16; r++) {
            int row = (r & 3) + 8 * (r >> 2) + 4 * half;
            float s = dred[row] + dred[32 + row] + dred[64 + row] + dred[96 + row];
            float inv = 1.0f / s;
            acc0[r] *= inv; acc1[r] *= inv; acc2[r] *= inv; acc3[r] *= inv;
        }
    }

    // ---- residual ----
    {
        #pragma unroll
        for (int kt = 0; kt < 8; kt++) {
            int ktt = w * 8 + kt;
            f16x8 ax = *(const f16x8*)(xh2 + ((size_t)ktt * 4096 + i) * 16 + half * 8);
            const f16* wb = Wrt2 + ((size_t)ktt * 1024 + h * 128 + l31) * 16 + half * 8;
            acc0 = __builtin_amdgcn_mfma_f32_32x32x16_f16(ax, *(const f16x8*)(wb), acc0, 0, 0, 0);
            acc1 = __builtin_amdgcn_mfma_f32_32x32x16_f16(ax, *(const f16x8*)(wb + 512), acc1, 0, 0, 0);
            acc2 = __builtin_amdgcn_mfma_f32_32x32x16_f16(ax, *(const f16x8*)(wb + 1024), acc2, 0, 0, 0);
            acc3 = __builtin_amdgcn_mfma_f32_32x32x16_f16(ax, *(const f16x8*)(wb + 1536), acc3, 0, 0, 0);
        }
    }

    // ---- cross-wave O reduction ----
    float* xredb = (float*)smem;
    __syncthreads();
    if (w >= 2) {
        float* dp = xredb + (w - 2) * 4352 + lane * 68;
        PUTACC(dp, 0, acc0); PUTACC(dp, 16, acc1); PUTACC(dp, 32, acc2); PUTACC(dp, 48, acc3);
    }
    __syncthreads();
    if (w < 2) {
        const float* dp = xredb + w * 4352 + lane * 68;
        ADDACC(dp, 0, acc0); ADDACC(dp, 16, acc1); ADDACC(dp, 32, acc2); ADDACC(dp, 48, acc3);
    }
    __syncthreads();
    if (w == 1) {
        float* dp = xredb + lane * 68;
        PUTACC(dp, 0, acc0); PUTACC(dp, 16, acc1); PUTACC(dp, 32, acc2); PUTACC(dp, 48, acc3);
    }
    __syncthreads();
    if (w == 0) {
        const float* dp = xredb + lane * 68;
        ADDACC(dp, 0, acc0); ADDACC(dp, 16, acc1); ADDACC(dp, 32, acc2); ADDACC(dp, 48, acc3);
        #pragma unroll
        for (int n = 0; n < 4; n++) {
            union { f32x16 v; f32x4 q[4]; } t;
            t.v = (n == 0) ? acc0 : (n == 1) ? acc1 : (n == 2) ? acc2 : acc3;
            int col = h * 128 + n * 32 + l31;
            float bv = bias[col];
            #pragma unroll
            for (int r = 0; r < 16; r++) {
                int row = i0 + (r & 3) + 8 * (r >> 2) + 4 * half;
                out[(size_t)row * 1024 + col] = t.v[r] + bv;
            }
        }
    }
}

extern "C" void kernel_launch(void* const* d_in, const int* in_sizes, int n_in,
                              void* d_out, int out_size, void* d_ws, size_t ws_size,
                              hipStream_t stream) {
    (void)in_sizes; (void)n_in; (void)out_size; (void)ws_size;
    const float* x     = (const float*)d_in[0];
    const int*   graph = (const int*)d_in[1];
    const float* W     = (const float*)d_in[2];
    const float* wi    = (const float*)d_in[3];
    const float* wj    = (const float*)d_in[4];
    const float* Wr    = (const float*)d_in[5];
    const float* bias  = (const float*)d_in[6];
    float* out = (float*)d_out;

    char* ws = (char*)d_ws;
    unsigned int* maskJ = (unsigned int*)ws;              // 2 MB  [128 jw][4096 i]
    f16* hbT2  = (f16*)(ws + (2u << 20));                 // 8 MB  [8][(j>>4)*128+f][j&15]
    f16* Wht2  = (f16*)(ws + (10u << 20));                // 1 MB  swizzled
    f16* Wrt2  = (f16*)(ws + (11u << 20));                // 1 MB  swizzled
    f16* xh2   = (f16*)(ws + (12u << 20));                // 4 MB  [32][4096][16] swizzled
    float* a2    = (float*)(ws + (16u << 20));            // 128 KB
    float* b2    = a2 + 8 * 4096;                         // 128 KB
    unsigned int* M2e = (unsigned int*)(b2 + 8 * 4096);   // 32 B

    hipLaunchKernelGGL(k_a, dim3(1536), dim3(256), 0, stream, x, xh2, W, Wht2, Wr, Wrt2, M2e);
    hipLaunchKernelGGL(k_b, dim3(2048), dim3(256), 0, stream, xh2, Wht2, hbT2,
                       wi, wj, a2, b2, M2e, graph, maskJ);
    hipLaunchKernelGGL(k_main, dim3(1024), dim3(256), 0, stream, xh2, hbT2, Wrt2, maskJ,
                       a2, b2, M2e, bias, out);
}

// Round 4
// 210.691 us; speedup vs baseline: 1.1342x; 1.1342x over previous
//
#include <hip/hip_runtime.h>
#include <hip/hip_fp16.h>

typedef _Float16 f16;
typedef _Float16 f16x8 __attribute__((ext_vector_type(8)));
typedef _Float16 f16x2v __attribute__((ext_vector_type(2)));
typedef __fp16 h16x2 __attribute__((ext_vector_type(2)));
typedef float f32x4 __attribute__((ext_vector_type(4)));
typedef float f32x16 __attribute__((ext_vector_type(16)));

#define LOG2E 1.4426950408889634f
#define NSL 0.2f

// ---------------- Kernel A: xcvt + swizzled weight transposes + M2e init ----------------
__global__ __launch_bounds__(256) void k_a(const float* __restrict__ x,
                                           f16* __restrict__ xh2,
                                           const float* __restrict__ W,
                                           f16* __restrict__ Wht2,
                                           const float* __restrict__ Wr,
                                           f16* __restrict__ Wrt2,
                                           unsigned int* __restrict__ M2e) {
    __shared__ float tile[32][33];
    int bx = blockIdx.x;
    int tid = threadIdx.x;
    if (bx == 0 && tid < 8) M2e[tid] = 0x007FFFFFu;  // enc(-inf)
    if (bx < 512) {
        int id = bx * 256 + tid;   // 131072
        int row = id & 4095, kt = id >> 12;
        const float4* xs = (const float4*)(x + (size_t)row * 512 + kt * 16);
        float4 u0 = xs[0], u1 = xs[1], u2 = xs[2], u3 = xs[3];
        union { int4 a[2]; h16x2 p[8]; } px;
        px.p[0] = __builtin_amdgcn_cvt_pkrtz(u0.x, u0.y);
        px.p[1] = __builtin_amdgcn_cvt_pkrtz(u0.z, u0.w);
        px.p[2] = __builtin_amdgcn_cvt_pkrtz(u1.x, u1.y);
        px.p[3] = __builtin_amdgcn_cvt_pkrtz(u1.z, u1.w);
        px.p[4] = __builtin_amdgcn_cvt_pkrtz(u2.x, u2.y);
        px.p[5] = __builtin_amdgcn_cvt_pkrtz(u2.z, u2.w);
        px.p[6] = __builtin_amdgcn_cvt_pkrtz(u3.x, u3.y);
        px.p[7] = __builtin_amdgcn_cvt_pkrtz(u3.z, u3.w);
        int4* d = (int4*)(xh2 + ((size_t)kt * 4096 + row) * 16);
        d[0] = px.a[0]; d[1] = px.a[1];
    } else {
        const float* in; f16* out; int C, S, bxx, byy;
        if (bx < 1024) { int id = bx - 512;  in = W;  out = Wht2; C = 128;  S = 128;  bxx = id & 3;  byy = id >> 2; }
        else           { int id = bx - 1024; in = Wr; out = Wrt2; C = 1024; S = 1024; bxx = id & 31; byy = id >> 5; }
        int tx = tid & 31, ty = tid >> 5;
        int c0 = bxx * 32, r0 = byy * 32;
        for (int rr = ty; rr < 32; rr += 8)
            tile[rr][tx] = in[(r0 + rr) * C + c0 + tx];
        __syncthreads();
        for (int rr = ty; rr < 32; rr += 8) {
            int m = r0 + tx, f = c0 + rr;
            out[(size_t)((m >> 4) * S + f) * 16 + (m & 15)] = (f16)tile[tx][rr];
        }
    }
}

// ---------------- Kernel B (fused): gemm_h (blocks 0..1023) + graph bitmask (1024..2047) ----------------
__global__ __launch_bounds__(256, 4) void k_b(const f16* __restrict__ xh2,
                                              const f16* __restrict__ Wht2,
                                              f16* __restrict__ hbT2,
                                              const float* __restrict__ wi,
                                              const float* __restrict__ wj,
                                              float* __restrict__ a2,
                                              float* __restrict__ b2,
                                              unsigned int* __restrict__ M2e,
                                              const int* __restrict__ graph,
                                              unsigned int* __restrict__ maskJ) {
    __shared__ float swi[128], swj[128];
    __shared__ float pwa[4][32], pwb[4][32];
    __shared__ unsigned long long bal[4][64];
    int bx = blockIdx.x;
    int tid = threadIdx.x;
    int w = tid >> 6, lane = tid & 63;

    if (bx >= 1024) {
        // ---- mask part ----
        int gw = (bx - 1024) * 4 + w;
        int ti = gw & 63, tj = gw >> 6;
        int i0 = ti * 64, j0 = tj * 64;
        #pragma unroll 8
        for (int k = 0; k < 64; k++) {
            int g = graph[(j0 + k) * 4096 + i0 + lane];
            unsigned long long b = __ballot(g > 0);
            if (lane == 0) bal[w][k] = b;
        }
        __syncthreads();
        unsigned long long word = 0;
        #pragma unroll 8
        for (int k = 0; k < 64; k++) {
            word |= ((bal[w][k] >> lane) & 1ull) << k;
        }
        int jw = j0 >> 5;
        maskJ[(size_t)jw * 4096 + i0 + lane]       = (unsigned int)word;
        maskJ[(size_t)(jw + 1) * 4096 + i0 + lane] = (unsigned int)(word >> 32);
        return;
    }

    // ---- gemm part ----
    int h = bx & 7, jb = bx >> 3;        // 128 j-tiles of 32
    int j0 = jb * 32;
    int ln = lane & 15, q = lane >> 4;
    if (tid < 128) { swi[tid] = wi[h * 128 + tid]; swj[tid] = wj[h * 128 + tid]; }
    __syncthreads();

    int ko = (q & 1) * 8;
    const f16* pa = Wht2 + ((size_t)(h * 512) * 8 + (size_t)(q >> 1) * 128 + w * 32 + ln) * 16 + ko;
    const f16* pb = xh2 + ((size_t)(q >> 1) * 4096 + j0 + ln) * 16 + ko;

    f32x4 acc00 = {}, acc01 = {}, acc10 = {}, acc11 = {};

    f16x8 ra0 = *(const f16x8*)(pa);
    f16x8 ra1 = *(const f16x8*)(pa + 256);
    f16x8 rb0 = *(const f16x8*)(pb);
    f16x8 rb1 = *(const f16x8*)(pb + 256);

    for (int kk = 0; kk < 8; kk++) {
        f16x8 sa0 = *(const f16x8*)(pa + 4096);
        f16x8 sa1 = *(const f16x8*)(pa + 4096 + 256);
        f16x8 sb0 = *(const f16x8*)(pb + 131072);
        f16x8 sb1 = *(const f16x8*)(pb + 131072 + 256);
        acc00 = __builtin_amdgcn_mfma_f32_16x16x32_f16(ra0, rb0, acc00, 0, 0, 0);
        acc01 = __builtin_amdgcn_mfma_f32_16x16x32_f16(ra0, rb1, acc01, 0, 0, 0);
        acc10 = __builtin_amdgcn_mfma_f32_16x16x32_f16(ra1, rb0, acc10, 0, 0, 0);
        acc11 = __builtin_amdgcn_mfma_f32_16x16x32_f16(ra1, rb1, acc11, 0, 0, 0);
        pa += 8192; pb += 262144;
        ra0 = *(const f16x8*)(pa);
        ra1 = *(const f16x8*)(pa + 256);
        rb0 = *(const f16x8*)(pb);
        rb1 = *(const f16x8*)(pb + 256);
        acc00 = __builtin_amdgcn_mfma_f32_16x16x32_f16(sa0, sb0, acc00, 0, 0, 0);
        acc01 = __builtin_amdgcn_mfma_f32_16x16x32_f16(sa0, sb1, acc01, 0, 0, 0);
        acc10 = __builtin_amdgcn_mfma_f32_16x16x32_f16(sa1, sb0, acc10, 0, 0, 0);
        acc11 = __builtin_amdgcn_mfma_f32_16x16x32_f16(sa1, sb1, acc11, 0, 0, 0);
    }

    size_t hb = (size_t)h * 524288 + (size_t)(j0 >> 4) * 2048;
    #pragma unroll
    for (int r = 0; r < 4; r++) {
        int f0 = w * 32 + q * 4 + r;
        hbT2[hb + f0 * 16 + ln]                 = (f16)acc00[r];
        hbT2[hb + 2048 + f0 * 16 + ln]          = (f16)acc01[r];
        hbT2[hb + (f0 + 16) * 16 + ln]          = (f16)acc10[r];
        hbT2[hb + 2048 + (f0 + 16) * 16 + ln]   = (f16)acc11[r];
    }

    float pa0 = 0.f, pb0 = 0.f, pa1 = 0.f, pb1 = 0.f;
    #pragma unroll
    for (int r = 0; r < 4; r++) {
        int f0 = w * 32 + q * 4 + r;
        float w0 = swi[f0], jv0 = swj[f0];
        float w1 = swi[f0 + 16], jv1 = swj[f0 + 16];
        pa0 += acc00[r] * w0 + acc10[r] * w1;
        pb0 += acc00[r] * jv0 + acc10[r] * jv1;
        pa1 += acc01[r] * w0 + acc11[r] * w1;
        pb1 += acc01[r] * jv0 + acc11[r] * jv1;
    }
    pa0 += __shfl_xor(pa0, 16); pa0 += __shfl_xor(pa0, 32);
    pb0 += __shfl_xor(pb0, 16); pb0 += __shfl_xor(pb0, 32);
    pa1 += __shfl_xor(pa1, 16); pa1 += __shfl_xor(pa1, 32);
    pb1 += __shfl_xor(pb1, 16); pb1 += __shfl_xor(pb1, 32);
    if (lane < 16) {
        pwa[w][ln] = pa0;      pwb[w][ln] = pb0;
        pwa[w][16 + ln] = pa1; pwb[w][16 + ln] = pb1;
    }
    __syncthreads();
    if (tid < 32) {
        int jj = tid;
        float pav = (pwa[0][jj] + pwa[1][jj]) + (pwa[2][jj] + pwa[3][jj]);
        float pbv = (pwb[0][jj] + pwb[1][jj]) + (pwb[2][jj] + pwb[3][jj]);
        a2[h * 4096 + j0 + jj] = pav * LOG2E;
        float bb = pbv * LOG2E;
        b2[h * 4096 + j0 + jj] = bb;
        float m = bb;
        m = fmaxf(m, __shfl_xor(m, 1, 32));
        m = fmaxf(m, __shfl_xor(m, 2, 32));
        m = fmaxf(m, __shfl_xor(m, 4, 32));
        m = fmaxf(m, __shfl_xor(m, 8, 32));
        m = fmaxf(m, __shfl_xor(m, 16, 32));
        if (jj == 0) {
            unsigned u = __float_as_uint(m);
            unsigned enc = (u & 0x80000000u) ? ~u : (u | 0x80000000u);
            atomicMax(&M2e[h], enc);
        }
    }
}

// ---------------- Kernel 6 helpers ----------------
// PGEN2: build one 16-j attention fragment for row set (A1,A2 = per-row factors),
// accumulating the row denominator into DS.
#define PGEN2(af, m8, qv, qw, A1, A2, DS)                                            \
    {                                                                                \
        union { int4 i4; unsigned u[4]; } uv, uw;                                    \
        uv.i4 = (qv); uw.i4 = (qw);                                                  \
        f16x2v dl = {(_Float16)0, (_Float16)0};                                      \
        _Pragma("unroll")                                                            \
        for (int p = 0; p < 4; p++) {                                                \
            union { unsigned u; f16x2v v; } b1, b2x, mm;                             \
            b1.u = uv.u[p]; b2x.u = uw.u[p];                                         \
            f16x2v pr1 = (A1) * b1.v;                                                \
            f16x2v pr2 = (A2) * b2x.v;                                               \
            mm.v = __builtin_elementwise_max(pr1, pr2);                              \
            int mlo = -(int)(((m8) >> (2 * p)) & 1u);                                \
            int mhi = -(int)(((m8) >> (2 * p + 1)) & 1u);                            \
            unsigned comb = ((unsigned)mlo & 0xFFFFu) | ((unsigned)mhi & 0xFFFF0000u);\
            mm.u &= comb;                                                            \
            af.u[p] = mm.u;                                                          \
            dl += mm.v;                                                              \
        }                                                                            \
        DS += (float)dl.x + (float)dl.y;                                             \
    }

#define PUTACC(dp, off, accv)                                                    \
    {                                                                            \
        union { f32x16 v; f32x4 q[4]; } t; t.v = (accv);                         \
        *(f32x4*)((dp) + (off))      = t.q[0];                                   \
        *(f32x4*)((dp) + (off) + 4)  = t.q[1];                                   \
        *(f32x4*)((dp) + (off) + 8)  = t.q[2];                                   \
        *(f32x4*)((dp) + (off) + 12) = t.q[3];                                   \
    }

#define ADDACC(dp, off, accv)                                                    \
    {                                                                            \
        union { f32x16 v; f32x4 q[4]; } t; t.v = (accv);                         \
        t.q[0] += *(const f32x4*)((dp) + (off));                                 \
        t.q[1] += *(const f32x4*)((dp) + (off) + 4);                             \
        t.q[2] += *(const f32x4*)((dp) + (off) + 8);                             \
        t.q[3] += *(const f32x4*)((dp) + (off) + 12);                            \
        (accv) = t.v;                                                            \
    }

// ---------------- Kernel 6: main — 64-row i-tiles (2x compute per hbT2 load, half the
// blocks/head -> half L2 re-read + half table-build), baseline 2-half-phase rotation,
// 2 waves/SIMD ----------------
__global__ __launch_bounds__(256, 2) void k_main(const f16* __restrict__ xh2,
                                                 const f16* __restrict__ hbT2,
                                                 const f16* __restrict__ Wrt2,
                                                 const unsigned int* __restrict__ maskJ,
                                                 const float* __restrict__ a2,
                                                 const float* __restrict__ b2,
                                                 const unsigned int* __restrict__ M2e,
                                                 const float* __restrict__ bias,
                                                 float* __restrict__ out) {
    // [0,33024) mask[64][129] | [33024,41216) Bv | [41216,49408) Bw | pad for tail overreads
    __shared__ char smem[49664];
    __shared__ float dred[256];           // [wave][64 rows]

    unsigned int* mlds = (unsigned int*)smem;
    unsigned int* bvlds = (unsigned int*)(smem + 33024);
    unsigned int* bwlds = (unsigned int*)(smem + 41216);

    int bx = blockIdx.x;
    int h = bx & 7, it = bx >> 3;         // 64 i-tiles of 64 rows
    int i0 = it * 64;
    int tid = threadIdx.x;
    int w = tid >> 6, lane = tid & 63;
    int l31 = lane & 31, half = lane >> 5;
    int i = i0 + l31;

    unsigned enc = M2e[h];
    unsigned um = (enc & 0x80000000u) ? (enc & 0x7FFFFFFFu) : ~enc;
    float M2 = __uint_as_float(um);

    // ---- build Bv/Bw tables in LDS from b2 + stage mask strip (64 rows) ----
    {
        const float2* bsrc = (const float2*)(b2 + h * 4096);
        #pragma unroll
        for (int c = 0; c < 8; c++) {
            int p = tid + c * 256;                 // 2048 j-pairs
            float2 tb = bsrc[p];
            float t0 = tb.x - M2, t1 = tb.y - M2;
            union { h16x2 pp; unsigned ii; } k1, k2;
            k1.pp = __builtin_amdgcn_cvt_pkrtz(exp2f(t0), exp2f(t1));
            k2.pp = __builtin_amdgcn_cvt_pkrtz(exp2f(NSL * t0), exp2f(NSL * t1));
            bvlds[p] = k1.ii;
            bwlds[p] = k2.ii;
        }
        #pragma unroll
        for (int c = 0; c < 32; c++) {
            int e = tid + c * 256;                 // e = jw*64 + ii
            int jw = e >> 6, ii = e & 63;
            mlds[ii * 129 + jw] = maskJ[(size_t)jw * 4096 + i0 + ii];
        }
    }

    // ---- per-row A factors (two row sets: i0+l31 and i0+32+l31) ----
    float avL = a2[h * 4096 + i];
    float avH = a2[h * 4096 + i + 32];
    float uuL = avL + M2, uuH = avH + M2;
    float mvL = fmaxf(uuL, NSL * uuL);
    float mvH = fmaxf(uuH, NSL * uuH);
    union { h16x2 pp; f16x2v v; } apL, apH;
    apL.pp = __builtin_amdgcn_cvt_pkrtz(exp2f(uuL - mvL), exp2f(NSL * uuL - mvL));
    apH.pp = __builtin_amdgcn_cvt_pkrtz(exp2f(uuH - mvH), exp2f(NSL * uuH - mvH));
    f16x2v ApL1 = {apL.v.x, apL.v.x};
    f16x2v ApL2 = {apL.v.y, apL.v.y};
    f16x2v ApH1 = {apH.v.x, apH.v.x};
    f16x2v ApH2 = {apH.v.y, apH.v.y};

    f32x16 accL0 = {}, accL1 = {}, accL2 = {}, accL3 = {};
    f32x16 accH0 = {}, accH1 = {}, accH2 = {}, accH3 = {};
    float dsumL = 0.f, dsumH = 0.f;

    int J0 = w * 1024;
    const f16* bb = hbT2 + (size_t)h * 524288 + ((size_t)(J0 >> 4) * 128 + l31) * 16 + half * 8;
    const unsigned int* bpv = bvlds + (J0 >> 1) + half * 4;
    const unsigned int* bpw = bwlds + (J0 >> 1) + half * 4;
    const unsigned int* mrowL = mlds + l31 * 129 + (J0 >> 5);
    const unsigned int* mrowH = mlds + (l31 + 32) * 129 + (J0 >> 5);

    int sh0 = half << 3;
    int sh1 = 16 + (half << 3);

    __syncthreads();

    // prologue
    f16x8 fa0 = *(const f16x8*)(bb);
    f16x8 fa1 = *(const f16x8*)(bb + 512);
    f16x8 fa2 = *(const f16x8*)(bb + 1024);
    f16x8 fa3 = *(const f16x8*)(bb + 1536);
    int4 qv0 = ((const int4*)(bpv))[0];
    int4 qw0 = ((const int4*)(bpw))[0];
    unsigned mwcL = mrowL[0];
    unsigned mwcH = mrowH[0];

    for (int tp = 0; tp < 32; tp++) {
        int t0 = tp * 2;
        const f16* s1 = bb + (size_t)(t0 + 1) * 2048;
        f16x8 fb0 = *(const f16x8*)(s1);
        f16x8 fb1 = *(const f16x8*)(s1 + 512);
        f16x8 fb2 = *(const f16x8*)(s1 + 1024);
        f16x8 fb3 = *(const f16x8*)(s1 + 1536);
        int4 qv1 = *(const int4*)(bpv + (t0 + 1) * 8);
        int4 qw1 = *(const int4*)(bpw + (t0 + 1) * 8);
        unsigned mwnL = mrowL[tp + 1];
        unsigned mwnH = mrowH[tp + 1];

        {
            union { f16x8 v; unsigned u[4]; } af;
            PGEN2(af, mwcL >> sh0, qv0, qw0, ApL1, ApL2, dsumL);
            accL0 = __builtin_amdgcn_mfma_f32_32x32x16_f16(af.v, fa0, accL0, 0, 0, 0);
            accL1 = __builtin_amdgcn_mfma_f32_32x32x16_f16(af.v, fa1, accL1, 0, 0, 0);
            accL2 = __builtin_amdgcn_mfma_f32_32x32x16_f16(af.v, fa2, accL2, 0, 0, 0);
            accL3 = __builtin_amdgcn_mfma_f32_32x32x16_f16(af.v, fa3, accL3, 0, 0, 0);
        }
        {
            union { f16x8 v; unsigned u[4]; } af;
            PGEN2(af, mwcH >> sh0, qv0, qw0, ApH1, ApH2, dsumH);
            accH0 = __builtin_amdgcn_mfma_f32_32x32x16_f16(af.v, fa0, accH0, 0, 0, 0);
            accH1 = __builtin_amdgcn_mfma_f32_32x32x16_f16(af.v, fa1, accH1, 0, 0, 0);
            accH2 = __builtin_amdgcn_mfma_f32_32x32x16_f16(af.v, fa2, accH2, 0, 0, 0);
            accH3 = __builtin_amdgcn_mfma_f32_32x32x16_f16(af.v, fa3, accH3, 0, 0, 0);
        }

        const f16* s2 = bb + (size_t)(t0 + 2) * 2048;
        fa0 = *(const f16x8*)(s2);
        fa1 = *(const f16x8*)(s2 + 512);
        fa2 = *(const f16x8*)(s2 + 1024);
        fa3 = *(const f16x8*)(s2 + 1536);
        qv0 = *(const int4*)(bpv + (t0 + 2) * 8);
        qw0 = *(const int4*)(bpw + (t0 + 2) * 8);

        {
            union { f16x8 v; unsigned u[4]; } af;
            PGEN2(af, mwcL >> sh1, qv1, qw1, ApL1, ApL2, dsumL);
            accL0 = __builtin_amdgcn_mfma_f32_32x32x16_f16(af.v, fb0, accL0, 0, 0, 0);
            accL1 = __builtin_amdgcn_mfma_f32_32x32x16_f16(af.v, fb1, accL1, 0, 0, 0);
            accL2 = __builtin_amdgcn_mfma_f32_32x32x16_f16(af.v, fb2, accL2, 0, 0, 0);
            accL3 = __builtin_amdgcn_mfma_f32_32x32x16_f16(af.v, fb3, accL3, 0, 0, 0);
        }
        {
            union { f16x8 v; unsigned u[4]; } af;
            PGEN2(af, mwcH >> sh1, qv1, qw1, ApH1, ApH2, dsumH);
            accH0 = __builtin_amdgcn_mfma_f32_32x32x16_f16(af.v, fb0, accH0, 0, 0, 0);
            accH1 = __builtin_amdgcn_mfma_f32_32x32x16_f16(af.v, fb1, accH1, 0, 0, 0);
            accH2 = __builtin_amdgcn_mfma_f32_32x32x16_f16(af.v, fb2, accH2, 0, 0, 0);
            accH3 = __builtin_amdgcn_mfma_f32_32x32x16_f16(af.v, fb3, accH3, 0, 0, 0);
        }
        mwcL = mwnL;
        mwcH = mwnH;
    }

    // ---- denominator ----
    dsumL += __shfl(dsumL, lane ^ 32);
    dsumH += __shfl(dsumH, lane ^ 32);
    if (lane < 32) {
        dred[w * 64 + l31] = dsumL;
        dred[w * 64 + 32 + l31] = dsumH;
    }
    __syncthreads();
    {
        #pragma unroll
        for (int r = 0; r < 16; r++) {
            int row = (r & 3) + 8 * (r >> 2) + 4 * half;
            float sL = dred[row] + dred[64 + row] + dred[128 + row] + dred[192 + row];
            float sH = dred[32 + row] + dred[96 + row] + dred[160 + row] + dred[224 + row];
            float invL = 1.0f / sL;
            float invH = 1.0f / sH;
            accL0[r] *= invL; accL1[r] *= invL; accL2[r] *= invL; accL3[r] *= invL;
            accH0[r] *= invH; accH1[r] *= invH; accH2[r] *= invH; accH3[r] *= invH;
        }
    }

    // ---- residual (per-wave partial over K/4, summed in cross-wave reduction) ----
    {
        #pragma unroll
        for (int kt = 0; kt < 8; kt++) {
            int ktt = w * 8 + kt;
            f16x8 axL = *(const f16x8*)(xh2 + ((size_t)ktt * 4096 + i) * 16 + half * 8);
            f16x8 axH = *(const f16x8*)(xh2 + ((size_t)ktt * 4096 + i + 32) * 16 + half * 8);
            const f16* wb = Wrt2 + ((size_t)ktt * 1024 + h * 128 + l31) * 16 + half * 8;
            f16x8 wb0 = *(const f16x8*)(wb);
            f16x8 wb1 = *(const f16x8*)(wb + 512);
            f16x8 wb2 = *(const f16x8*)(wb + 1024);
            f16x8 wb3 = *(const f16x8*)(wb + 1536);
            accL0 = __builtin_amdgcn_mfma_f32_32x32x16_f16(axL, wb0, accL0, 0, 0, 0);
            accL1 = __builtin_amdgcn_mfma_f32_32x32x16_f16(axL, wb1, accL1, 0, 0, 0);
            accL2 = __builtin_amdgcn_mfma_f32_32x32x16_f16(axL, wb2, accL2, 0, 0, 0);
            accL3 = __builtin_amdgcn_mfma_f32_32x32x16_f16(axL, wb3, accL3, 0, 0, 0);
            accH0 = __builtin_amdgcn_mfma_f32_32x32x16_f16(axH, wb0, accH0, 0, 0, 0);
            accH1 = __builtin_amdgcn_mfma_f32_32x32x16_f16(axH, wb1, accH1, 0, 0, 0);
            accH2 = __builtin_amdgcn_mfma_f32_32x32x16_f16(axH, wb2, accH2, 0, 0, 0);
            accH3 = __builtin_amdgcn_mfma_f32_32x32x16_f16(axH, wb3, accH3, 0, 0, 0);
        }
    }

    // ---- cross-wave O reduction: pass L (rows i0..i0+31), then pass H (+32) ----
    float* xredb = (float*)smem;

    // pass L
    __syncthreads();
    if (w >= 2) {
        float* dp = xredb + (w - 2) * 4352 + lane * 68;
        PUTACC(dp, 0, accL0); PUTACC(dp, 16, accL1); PUTACC(dp, 32, accL2); PUTACC(dp, 48, accL3);
    }
    __syncthreads();
    if (w < 2) {
        const float* dp = xredb + w * 4352 + lane * 68;
        ADDACC(dp, 0, accL0); ADDACC(dp, 16, accL1); ADDACC(dp, 32, accL2); ADDACC(dp, 48, accL3);
    }
    __syncthreads();
    if (w == 1) {
        float* dp = xredb + lane * 68;
        PUTACC(dp, 0, accL0); PUTACC(dp, 16, accL1); PUTACC(dp, 32, accL2); PUTACC(dp, 48, accL3);
    }
    __syncthreads();
    if (w == 0) {
        const float* dp = xredb + lane * 68;
        ADDACC(dp, 0, accL0); ADDACC(dp, 16, accL1); ADDACC(dp, 32, accL2); ADDACC(dp, 48, accL3);
        #pragma unroll
        for (int n = 0; n < 4; n++) {
            union { f32x16 v; f32x4 q[4]; } t;
            t.v = (n == 0) ? accL0 : (n == 1) ? accL1 : (n == 2) ? accL2 : accL3;
            int col = h * 128 + n * 32 + l31;
            float bv = bias[col];
            #pragma unroll
            for (int r = 0; r < 16; r++) {
                int row = i0 + (r & 3) + 8 * (r >> 2) + 4 * half;
                out[(size_t)row * 1024 + col] = t.v[r] + bv;
            }
        }
    }

    // pass H
    __syncthreads();
    if (w >= 2) {
        float* dp = xredb + (w - 2) * 4352 + lane * 68;
        PUTACC(dp, 0, accH0); PUTACC(dp, 16, accH1); PUTACC(dp, 32, accH2); PUTACC(dp, 48, accH3);
    }
    __syncthreads();
    if (w < 2) {
        const float* dp = xredb + w * 4352 + lane * 68;
        ADDACC(dp, 0, accH0); ADDACC(dp, 16, accH1); ADDACC(dp, 32, accH2); ADDACC(dp, 48, accH3);
    }
    __syncthreads();
    if (w == 1) {
        float* dp = xredb + lane * 68;
        PUTACC(dp, 0, accH0); PUTACC(dp, 16, accH1); PUTACC(dp, 32, accH2); PUTACC(dp, 48, accH3);
    }
    __syncthreads();
    if (w == 0) {
        const float* dp = xredb + lane * 68;
        ADDACC(dp, 0, accH0); ADDACC(dp, 16, accH1); ADDACC(dp, 32, accH2); ADDACC(dp, 48, accH3);
        #pragma unroll
        for (int n = 0; n < 4; n++) {
            union { f32x16 v; f32x4 q[4]; } t;
            t.v = (n == 0) ? accH0 : (n == 1) ? accH1 : (n == 2) ? accH2 : accH3;
            int col = h * 128 + n * 32 + l31;
            float bv = bias[col];
            #pragma unroll
            for (int r = 0; r < 16; r++) {
                int row = i0 + 32 + (r & 3) + 8 * (r >> 2) + 4 * half;
                out[(size_t)row * 1024 + col] = t.v[r] + bv;
            }
        }
    }
}

extern "C" void kernel_launch(void* const* d_in, const int* in_sizes, int n_in,
                              void* d_out, int out_size, void* d_ws, size_t ws_size,
                              hipStream_t stream) {
    (void)in_sizes; (void)n_in; (void)out_size; (void)ws_size;
    const float* x     = (const float*)d_in[0];
    const int*   graph = (const int*)d_in[1];
    const float* W     = (const float*)d_in[2];
    const float* wi    = (const float*)d_in[3];
    const float* wj    = (const float*)d_in[4];
    const float* Wr    = (const float*)d_in[5];
    const float* bias  = (const float*)d_in[6];
    float* out = (float*)d_out;

    char* ws = (char*)d_ws;
    unsigned int* maskJ = (unsigned int*)ws;              // 2 MB  [128 jw][4096 i]
    f16* hbT2  = (f16*)(ws + (2u << 20));                 // 8 MB  [8][(j>>4)*128+f][j&15]
    f16* Wht2  = (f16*)(ws + (10u << 20));                // 1 MB  swizzled
    f16* Wrt2  = (f16*)(ws + (11u << 20));                // 1 MB  swizzled
    f16* xh2   = (f16*)(ws + (12u << 20));                // 4 MB  [32][4096][16] swizzled
    float* a2    = (float*)(ws + (16u << 20));            // 128 KB
    float* b2    = a2 + 8 * 4096;                         // 128 KB
    unsigned int* M2e = (unsigned int*)(b2 + 8 * 4096);   // 32 B

    hipLaunchKernelGGL(k_a, dim3(1536), dim3(256), 0, stream, x, xh2, W, Wht2, Wr, Wrt2, M2e);
    hipLaunchKernelGGL(k_b, dim3(2048), dim3(256), 0, stream, xh2, Wht2, hbT2,
                       wi, wj, a2, b2, M2e, graph, maskJ);
    hipLaunchKernelGGL(k_main, dim3(512), dim3(256), 0, stream, xh2, hbT2, Wrt2, maskJ,
                       a2, b2, M2e, bias, out);
}

// Round 5
// 183.108 us; speedup vs baseline: 1.3051x; 1.1506x over previous
//
#include <hip/hip_runtime.h>
#include <hip/hip_fp16.h>

typedef _Float16 f16;
typedef _Float16 f16x8 __attribute__((ext_vector_type(8)));
typedef _Float16 f16x2v __attribute__((ext_vector_type(2)));
typedef __fp16 h16x2 __attribute__((ext_vector_type(2)));
typedef float f32x4 __attribute__((ext_vector_type(4)));
typedef float f32x16 __attribute__((ext_vector_type(16)));

#define LOG2E 1.4426950408889634f
#define NSL 0.2f

// ---------------- Kernel A: xcvt + swizzled weight transposes + M2e init ----------------
__global__ __launch_bounds__(256) void k_a(const float* __restrict__ x,
                                           f16* __restrict__ xh2,
                                           const float* __restrict__ W,
                                           f16* __restrict__ Wht2,
                                           const float* __restrict__ Wr,
                                           f16* __restrict__ Wrt2,
                                           unsigned int* __restrict__ M2e) {
    __shared__ float tile[32][33];
    int bx = blockIdx.x;
    int tid = threadIdx.x;
    if (bx == 0 && tid < 8) M2e[tid] = 0x007FFFFFu;  // enc(-inf)
    if (bx < 512) {
        int id = bx * 256 + tid;   // 131072
        int row = id & 4095, kt = id >> 12;
        const float4* xs = (const float4*)(x + (size_t)row * 512 + kt * 16);
        float4 u0 = xs[0], u1 = xs[1], u2 = xs[2], u3 = xs[3];
        union { int4 a[2]; h16x2 p[8]; } px;
        px.p[0] = __builtin_amdgcn_cvt_pkrtz(u0.x, u0.y);
        px.p[1] = __builtin_amdgcn_cvt_pkrtz(u0.z, u0.w);
        px.p[2] = __builtin_amdgcn_cvt_pkrtz(u1.x, u1.y);
        px.p[3] = __builtin_amdgcn_cvt_pkrtz(u1.z, u1.w);
        px.p[4] = __builtin_amdgcn_cvt_pkrtz(u2.x, u2.y);
        px.p[5] = __builtin_amdgcn_cvt_pkrtz(u2.z, u2.w);
        px.p[6] = __builtin_amdgcn_cvt_pkrtz(u3.x, u3.y);
        px.p[7] = __builtin_amdgcn_cvt_pkrtz(u3.z, u3.w);
        int4* d = (int4*)(xh2 + ((size_t)kt * 4096 + row) * 16);
        d[0] = px.a[0]; d[1] = px.a[1];
    } else {
        const float* in; f16* out; int C, S, bxx, byy;
        if (bx < 1024) { int id = bx - 512;  in = W;  out = Wht2; C = 128;  S = 128;  bxx = id & 3;  byy = id >> 2; }
        else           { int id = bx - 1024; in = Wr; out = Wrt2; C = 1024; S = 1024; bxx = id & 31; byy = id >> 5; }
        int tx = tid & 31, ty = tid >> 5;
        int c0 = bxx * 32, r0 = byy * 32;
        for (int rr = ty; rr < 32; rr += 8)
            tile[rr][tx] = in[(r0 + rr) * C + c0 + tx];
        __syncthreads();
        for (int rr = ty; rr < 32; rr += 8) {
            int m = r0 + tx, f = c0 + rr;
            out[(size_t)((m >> 4) * S + f) * 16 + (m & 15)] = (f16)tile[tx][rr];
        }
    }
}

// ---------------- Kernel B (fused): gemm_h (blocks 0..1023) + graph bitmask (1024..3071) ----------------
// Mask build: ballot-free, 32 independent dword loads per thread -> deep MLP, HBM-BW-bound.
__global__ __launch_bounds__(256, 4) void k_b(const f16* __restrict__ xh2,
                                              const f16* __restrict__ Wht2,
                                              f16* __restrict__ hbT2,
                                              const float* __restrict__ wi,
                                              const float* __restrict__ wj,
                                              float* __restrict__ a2,
                                              float* __restrict__ b2,
                                              unsigned int* __restrict__ M2e,
                                              const int* __restrict__ graph,
                                              unsigned int* __restrict__ maskJ) {
    __shared__ float swi[128], swj[128];
    __shared__ float pwa[4][32], pwb[4][32];
    int bx = blockIdx.x;
    int tid = threadIdx.x;
    int w = tid >> 6, lane = tid & 63;

    if (bx >= 1024) {
        // ---- mask part: one thread per output word, 32-deep independent loads ----
        int e = (bx - 1024) * 256 + tid;       // 0..524287 = jw*4096 + i
        int jw = e >> 12, ii = e & 4095;
        const int* gp = graph + (size_t)(jw << 5) * 4096 + ii;
        int gv[32];
        #pragma unroll
        for (int k = 0; k < 32; k++) gv[k] = gp[(size_t)k * 4096];
        unsigned word = 0;
        #pragma unroll
        for (int k = 0; k < 32; k++) word |= (gv[k] > 0) ? (1u << k) : 0u;
        maskJ[e] = word;
        return;
    }

    // ---- gemm part ----
    int h = bx & 7, jb = bx >> 3;        // 128 j-tiles of 32
    int j0 = jb * 32;
    int ln = lane & 15, q = lane >> 4;
    if (tid < 128) { swi[tid] = wi[h * 128 + tid]; swj[tid] = wj[h * 128 + tid]; }
    __syncthreads();

    int ko = (q & 1) * 8;
    const f16* pa = Wht2 + ((size_t)(h * 512) * 8 + (size_t)(q >> 1) * 128 + w * 32 + ln) * 16 + ko;
    const f16* pb = xh2 + ((size_t)(q >> 1) * 4096 + j0 + ln) * 16 + ko;

    f32x4 acc00 = {}, acc01 = {}, acc10 = {}, acc11 = {};

    f16x8 ra0 = *(const f16x8*)(pa);
    f16x8 ra1 = *(const f16x8*)(pa + 256);
    f16x8 rb0 = *(const f16x8*)(pb);
    f16x8 rb1 = *(const f16x8*)(pb + 256);

    for (int kk = 0; kk < 8; kk++) {
        f16x8 sa0 = *(const f16x8*)(pa + 4096);
        f16x8 sa1 = *(const f16x8*)(pa + 4096 + 256);
        f16x8 sb0 = *(const f16x8*)(pb + 131072);
        f16x8 sb1 = *(const f16x8*)(pb + 131072 + 256);
        acc00 = __builtin_amdgcn_mfma_f32_16x16x32_f16(ra0, rb0, acc00, 0, 0, 0);
        acc01 = __builtin_amdgcn_mfma_f32_16x16x32_f16(ra0, rb1, acc01, 0, 0, 0);
        acc10 = __builtin_amdgcn_mfma_f32_16x16x32_f16(ra1, rb0, acc10, 0, 0, 0);
        acc11 = __builtin_amdgcn_mfma_f32_16x16x32_f16(ra1, rb1, acc11, 0, 0, 0);
        pa += 8192; pb += 262144;
        ra0 = *(const f16x8*)(pa);
        ra1 = *(const f16x8*)(pa + 256);
        rb0 = *(const f16x8*)(pb);
        rb1 = *(const f16x8*)(pb + 256);
        acc00 = __builtin_amdgcn_mfma_f32_16x16x32_f16(sa0, sb0, acc00, 0, 0, 0);
        acc01 = __builtin_amdgcn_mfma_f32_16x16x32_f16(sa0, sb1, acc01, 0, 0, 0);
        acc10 = __builtin_amdgcn_mfma_f32_16x16x32_f16(sa1, sb0, acc10, 0, 0, 0);
        acc11 = __builtin_amdgcn_mfma_f32_16x16x32_f16(sa1, sb1, acc11, 0, 0, 0);
    }

    size_t hb = (size_t)h * 524288 + (size_t)(j0 >> 4) * 2048;
    #pragma unroll
    for (int r = 0; r < 4; r++) {
        int f0 = w * 32 + q * 4 + r;
        hbT2[hb + f0 * 16 + ln]                 = (f16)acc00[r];
        hbT2[hb + 2048 + f0 * 16 + ln]          = (f16)acc01[r];
        hbT2[hb + (f0 + 16) * 16 + ln]          = (f16)acc10[r];
        hbT2[hb + 2048 + (f0 + 16) * 16 + ln]   = (f16)acc11[r];
    }

    float pa0 = 0.f, pb0 = 0.f, pa1 = 0.f, pb1 = 0.f;
    #pragma unroll
    for (int r = 0; r < 4; r++) {
        int f0 = w * 32 + q * 4 + r;
        float w0 = swi[f0], jv0 = swj[f0];
        float w1 = swi[f0 + 16], jv1 = swj[f0 + 16];
        pa0 += acc00[r] * w0 + acc10[r] * w1;
        pb0 += acc00[r] * jv0 + acc10[r] * jv1;
        pa1 += acc01[r] * w0 + acc11[r] * w1;
        pb1 += acc01[r] * jv0 + acc11[r] * jv1;
    }
    pa0 += __shfl_xor(pa0, 16); pa0 += __shfl_xor(pa0, 32);
    pb0 += __shfl_xor(pb0, 16); pb0 += __shfl_xor(pb0, 32);
    pa1 += __shfl_xor(pa1, 16); pa1 += __shfl_xor(pa1, 32);
    pb1 += __shfl_xor(pb1, 16); pb1 += __shfl_xor(pb1, 32);
    if (lane < 16) {
        pwa[w][ln] = pa0;      pwb[w][ln] = pb0;
        pwa[w][16 + ln] = pa1; pwb[w][16 + ln] = pb1;
    }
    __syncthreads();
    if (tid < 32) {
        int jj = tid;
        float pav = (pwa[0][jj] + pwa[1][jj]) + (pwa[2][jj] + pwa[3][jj]);
        float pbv = (pwb[0][jj] + pwb[1][jj]) + (pwb[2][jj] + pwb[3][jj]);
        a2[h * 4096 + j0 + jj] = pav * LOG2E;
        float bb = pbv * LOG2E;
        b2[h * 4096 + j0 + jj] = bb;
        float m = bb;
        m = fmaxf(m, __shfl_xor(m, 1, 32));
        m = fmaxf(m, __shfl_xor(m, 2, 32));
        m = fmaxf(m, __shfl_xor(m, 4, 32));
        m = fmaxf(m, __shfl_xor(m, 8, 32));
        m = fmaxf(m, __shfl_xor(m, 16, 32));
        if (jj == 0) {
            unsigned u = __float_as_uint(m);
            unsigned enc = (u & 0x80000000u) ? ~u : (u | 0x80000000u);
            atomicMax(&M2e[h], enc);
        }
    }
}

// ---------------- Kernel 6 helpers ----------------
// PGEN2: build one 16-j attention fragment for row set (A1,A2 = per-row factors),
// accumulating the row denominator into DS.
#define PGEN2(af, m8, qv, qw, A1, A2, DS)                                            \
    {                                                                                \
        union { int4 i4; unsigned u[4]; } uv, uw;                                    \
        uv.i4 = (qv); uw.i4 = (qw);                                                  \
        f16x2v dl = {(_Float16)0, (_Float16)0};                                      \
        _Pragma("unroll")                                                            \
        for (int p = 0; p < 4; p++) {                                                \
            union { unsigned u; f16x2v v; } b1, b2x, mm;                             \
            b1.u = uv.u[p]; b2x.u = uw.u[p];                                         \
            f16x2v pr1 = (A1) * b1.v;                                                \
            f16x2v pr2 = (A2) * b2x.v;                                               \
            mm.v = __builtin_elementwise_max(pr1, pr2);                              \
            int mlo = -(int)(((m8) >> (2 * p)) & 1u);                                \
            int mhi = -(int)(((m8) >> (2 * p + 1)) & 1u);                            \
            unsigned comb = ((unsigned)mlo & 0xFFFFu) | ((unsigned)mhi & 0xFFFF0000u);\
            mm.u &= comb;                                                            \
            af.u[p] = mm.u;                                                          \
            dl += mm.v;                                                              \
        }                                                                            \
        DS += (float)dl.x + (float)dl.y;                                             \
    }

#define PUTACC(dp, off, accv)                                                    \
    {                                                                            \
        union { f32x16 v; f32x4 q[4]; } t; t.v = (accv);                         \
        *(f32x4*)((dp) + (off))      = t.q[0];                                   \
        *(f32x4*)((dp) + (off) + 4)  = t.q[1];                                   \
        *(f32x4*)((dp) + (off) + 8)  = t.q[2];                                   \
        *(f32x4*)((dp) + (off) + 12) = t.q[3];                                   \
    }

#define ADDACC(dp, off, accv)                                                    \
    {                                                                            \
        union { f32x16 v; f32x4 q[4]; } t; t.v = (accv);                         \
        t.q[0] += *(const f32x4*)((dp) + (off));                                 \
        t.q[1] += *(const f32x4*)((dp) + (off) + 4);                             \
        t.q[2] += *(const f32x4*)((dp) + (off) + 8);                             \
        t.q[3] += *(const f32x4*)((dp) + (off) + 12);                            \
        (accv) = t.v;                                                            \
    }

// ---------------- Kernel 6: main — 64-row i-tiles (2x compute per hbT2 load, half the
// blocks/head -> half L2 re-read + half table-build), baseline 2-half-phase rotation,
// 2 waves/SIMD ----------------
__global__ __launch_bounds__(256, 2) void k_main(const f16* __restrict__ xh2,
                                                 const f16* __restrict__ hbT2,
                                                 const f16* __restrict__ Wrt2,
                                                 const unsigned int* __restrict__ maskJ,
                                                 const float* __restrict__ a2,
                                                 const float* __restrict__ b2,
                                                 const unsigned int* __restrict__ M2e,
                                                 const float* __restrict__ bias,
                                                 float* __restrict__ out) {
    // [0,33024) mask[64][129] | [33024,41216) Bv | [41216,49408) Bw | pad for tail overreads
    __shared__ char smem[49664];
    __shared__ float dred[256];           // [wave][64 rows]

    unsigned int* mlds = (unsigned int*)smem;
    unsigned int* bvlds = (unsigned int*)(smem + 33024);
    unsigned int* bwlds = (unsigned int*)(smem + 41216);

    int bx = blockIdx.x;
    int h = bx & 7, it = bx >> 3;         // 64 i-tiles of 64 rows
    int i0 = it * 64;
    int tid = threadIdx.x;
    int w = tid >> 6, lane = tid & 63;
    int l31 = lane & 31, half = lane >> 5;
    int i = i0 + l31;

    unsigned enc = M2e[h];
    unsigned um = (enc & 0x80000000u) ? (enc & 0x7FFFFFFFu) : ~enc;
    float M2 = __uint_as_float(um);

    // ---- build Bv/Bw tables in LDS from b2 + stage mask strip (64 rows) ----
    {
        const float2* bsrc = (const float2*)(b2 + h * 4096);
        #pragma unroll
        for (int c = 0; c < 8; c++) {
            int p = tid + c * 256;                 // 2048 j-pairs
            float2 tb = bsrc[p];
            float t0 = tb.x - M2, t1 = tb.y - M2;
            union { h16x2 pp; unsigned ii; } k1, k2;
            k1.pp = __builtin_amdgcn_cvt_pkrtz(exp2f(t0), exp2f(t1));
            k2.pp = __builtin_amdgcn_cvt_pkrtz(exp2f(NSL * t0), exp2f(NSL * t1));
            bvlds[p] = k1.ii;
            bwlds[p] = k2.ii;
        }
        #pragma unroll
        for (int c = 0; c < 32; c++) {
            int e = tid + c * 256;                 // e = jw*64 + ii
            int jw = e >> 6, ii = e & 63;
            mlds[ii * 129 + jw] = maskJ[(size_t)jw * 4096 + i0 + ii];
        }
    }

    // ---- per-row A factors (two row sets: i0+l31 and i0+32+l31) ----
    float avL = a2[h * 4096 + i];
    float avH = a2[h * 4096 + i + 32];
    float uuL = avL + M2, uuH = avH + M2;
    float mvL = fmaxf(uuL, NSL * uuL);
    float mvH = fmaxf(uuH, NSL * uuH);
    union { h16x2 pp; f16x2v v; } apL, apH;
    apL.pp = __builtin_amdgcn_cvt_pkrtz(exp2f(uuL - mvL), exp2f(NSL * uuL - mvL));
    apH.pp = __builtin_amdgcn_cvt_pkrtz(exp2f(uuH - mvH), exp2f(NSL * uuH - mvH));
    f16x2v ApL1 = {apL.v.x, apL.v.x};
    f16x2v ApL2 = {apL.v.y, apL.v.y};
    f16x2v ApH1 = {apH.v.x, apH.v.x};
    f16x2v ApH2 = {apH.v.y, apH.v.y};

    f32x16 accL0 = {}, accL1 = {}, accL2 = {}, accL3 = {};
    f32x16 accH0 = {}, accH1 = {}, accH2 = {}, accH3 = {};
    float dsumL = 0.f, dsumH = 0.f;

    int J0 = w * 1024;
    const f16* bb = hbT2 + (size_t)h * 524288 + ((size_t)(J0 >> 4) * 128 + l31) * 16 + half * 8;
    const unsigned int* bpv = bvlds + (J0 >> 1) + half * 4;
    const unsigned int* bpw = bwlds + (J0 >> 1) + half * 4;
    const unsigned int* mrowL = mlds + l31 * 129 + (J0 >> 5);
    const unsigned int* mrowH = mlds + (l31 + 32) * 129 + (J0 >> 5);

    int sh0 = half << 3;
    int sh1 = 16 + (half << 3);

    __syncthreads();

    // prologue
    f16x8 fa0 = *(const f16x8*)(bb);
    f16x8 fa1 = *(const f16x8*)(bb + 512);
    f16x8 fa2 = *(const f16x8*)(bb + 1024);
    f16x8 fa3 = *(const f16x8*)(bb + 1536);
    int4 qv0 = ((const int4*)(bpv))[0];
    int4 qw0 = ((const int4*)(bpw))[0];
    unsigned mwcL = mrowL[0];
    unsigned mwcH = mrowH[0];

    for (int tp = 0; tp < 32; tp++) {
        int t0 = tp * 2;
        const f16* s1 = bb + (size_t)(t0 + 1) * 2048;
        f16x8 fb0 = *(const f16x8*)(s1);
        f16x8 fb1 = *(const f16x8*)(s1 + 512);
        f16x8 fb2 = *(const f16x8*)(s1 + 1024);
        f16x8 fb3 = *(const f16x8*)(s1 + 1536);
        int4 qv1 = *(const int4*)(bpv + (t0 + 1) * 8);
        int4 qw1 = *(const int4*)(bpw + (t0 + 1) * 8);
        unsigned mwnL = mrowL[tp + 1];
        unsigned mwnH = mrowH[tp + 1];

        {
            union { f16x8 v; unsigned u[4]; } af;
            PGEN2(af, mwcL >> sh0, qv0, qw0, ApL1, ApL2, dsumL);
            accL0 = __builtin_amdgcn_mfma_f32_32x32x16_f16(af.v, fa0, accL0, 0, 0, 0);
            accL1 = __builtin_amdgcn_mfma_f32_32x32x16_f16(af.v, fa1, accL1, 0, 0, 0);
            accL2 = __builtin_amdgcn_mfma_f32_32x32x16_f16(af.v, fa2, accL2, 0, 0, 0);
            accL3 = __builtin_amdgcn_mfma_f32_32x32x16_f16(af.v, fa3, accL3, 0, 0, 0);
        }
        {
            union { f16x8 v; unsigned u[4]; } af;
            PGEN2(af, mwcH >> sh0, qv0, qw0, ApH1, ApH2, dsumH);
            accH0 = __builtin_amdgcn_mfma_f32_32x32x16_f16(af.v, fa0, accH0, 0, 0, 0);
            accH1 = __builtin_amdgcn_mfma_f32_32x32x16_f16(af.v, fa1, accH1, 0, 0, 0);
            accH2 = __builtin_amdgcn_mfma_f32_32x32x16_f16(af.v, fa2, accH2, 0, 0, 0);
            accH3 = __builtin_amdgcn_mfma_f32_32x32x16_f16(af.v, fa3, accH3, 0, 0, 0);
        }

        const f16* s2 = bb + (size_t)(t0 + 2) * 2048;
        fa0 = *(const f16x8*)(s2);
        fa1 = *(const f16x8*)(s2 + 512);
        fa2 = *(const f16x8*)(s2 + 1024);
        fa3 = *(const f16x8*)(s2 + 1536);
        qv0 = *(const int4*)(bpv + (t0 + 2) * 8);
        qw0 = *(const int4*)(bpw + (t0 + 2) * 8);

        {
            union { f16x8 v; unsigned u[4]; } af;
            PGEN2(af, mwcL >> sh1, qv1, qw1, ApL1, ApL2, dsumL);
            accL0 = __builtin_amdgcn_mfma_f32_32x32x16_f16(af.v, fb0, accL0, 0, 0, 0);
            accL1 = __builtin_amdgcn_mfma_f32_32x32x16_f16(af.v, fb1, accL1, 0, 0, 0);
            accL2 = __builtin_amdgcn_mfma_f32_32x32x16_f16(af.v, fb2, accL2, 0, 0, 0);
            accL3 = __builtin_amdgcn_mfma_f32_32x32x16_f16(af.v, fb3, accL3, 0, 0, 0);
        }
        {
            union { f16x8 v; unsigned u[4]; } af;
            PGEN2(af, mwcH >> sh1, qv1, qw1, ApH1, ApH2, dsumH);
            accH0 = __builtin_amdgcn_mfma_f32_32x32x16_f16(af.v, fb0, accH0, 0, 0, 0);
            accH1 = __builtin_amdgcn_mfma_f32_32x32x16_f16(af.v, fb1, accH1, 0, 0, 0);
            accH2 = __builtin_amdgcn_mfma_f32_32x32x16_f16(af.v, fb2, accH2, 0, 0, 0);
            accH3 = __builtin_amdgcn_mfma_f32_32x32x16_f16(af.v, fb3, accH3, 0, 0, 0);
        }
        mwcL = mwnL;
        mwcH = mwnH;
    }

    // ---- denominator ----
    dsumL += __shfl(dsumL, lane ^ 32);
    dsumH += __shfl(dsumH, lane ^ 32);
    if (lane < 32) {
        dred[w * 64 + l31] = dsumL;
        dred[w * 64 + 32 + l31] = dsumH;
    }
    __syncthreads();
    {
        #pragma unroll
        for (int r = 0; r < 16; r++) {
            int row = (r & 3) + 8 * (r >> 2) + 4 * half;
            float sL = dred[row] + dred[64 + row] + dred[128 + row] + dred[192 + row];
            float sH = dred[32 + row] + dred[96 + row] + dred[160 + row] + dred[224 + row];
            float invL = 1.0f / sL;
            float invH = 1.0f / sH;
            accL0[r] *= invL; accL1[r] *= invL; accL2[r] *= invL; accL3[r] *= invL;
            accH0[r] *= invH; accH1[r] *= invH; accH2[r] *= invH; accH3[r] *= invH;
        }
    }

    // ---- residual (per-wave partial over K/4, summed in cross-wave reduction) ----
    {
        #pragma unroll
        for (int kt = 0; kt < 8; kt++) {
            int ktt = w * 8 + kt;
            f16x8 axL = *(const f16x8*)(xh2 + ((size_t)ktt * 4096 + i) * 16 + half * 8);
            f16x8 axH = *(const f16x8*)(xh2 + ((size_t)ktt * 4096 + i + 32) * 16 + half * 8);
            const f16* wb = Wrt2 + ((size_t)ktt * 1024 + h * 128 + l31) * 16 + half * 8;
            f16x8 wb0 = *(const f16x8*)(wb);
            f16x8 wb1 = *(const f16x8*)(wb + 512);
            f16x8 wb2 = *(const f16x8*)(wb + 1024);
            f16x8 wb3 = *(const f16x8*)(wb + 1536);
            accL0 = __builtin_amdgcn_mfma_f32_32x32x16_f16(axL, wb0, accL0, 0, 0, 0);
            accL1 = __builtin_amdgcn_mfma_f32_32x32x16_f16(axL, wb1, accL1, 0, 0, 0);
            accL2 = __builtin_amdgcn_mfma_f32_32x32x16_f16(axL, wb2, accL2, 0, 0, 0);
            accL3 = __builtin_amdgcn_mfma_f32_32x32x16_f16(axL, wb3, accL3, 0, 0, 0);
            accH0 = __builtin_amdgcn_mfma_f32_32x32x16_f16(axH, wb0, accH0, 0, 0, 0);
            accH1 = __builtin_amdgcn_mfma_f32_32x32x16_f16(axH, wb1, accH1, 0, 0, 0);
            accH2 = __builtin_amdgcn_mfma_f32_32x32x16_f16(axH, wb2, accH2, 0, 0, 0);
            accH3 = __builtin_amdgcn_mfma_f32_32x32x16_f16(axH, wb3, accH3, 0, 0, 0);
        }
    }

    // ---- cross-wave O reduction: pass L (rows i0..i0+31), then pass H (+32) ----
    float* xredb = (float*)smem;

    // pass L
    __syncthreads();
    if (w >= 2) {
        float* dp = xredb + (w - 2) * 4352 + lane * 68;
        PUTACC(dp, 0, accL0); PUTACC(dp, 16, accL1); PUTACC(dp, 32, accL2); PUTACC(dp, 48, accL3);
    }
    __syncthreads();
    if (w < 2) {
        const float* dp = xredb + w * 4352 + lane * 68;
        ADDACC(dp, 0, accL0); ADDACC(dp, 16, accL1); ADDACC(dp, 32, accL2); ADDACC(dp, 48, accL3);
    }
    __syncthreads();
    if (w == 1) {
        float* dp = xredb + lane * 68;
        PUTACC(dp, 0, accL0); PUTACC(dp, 16, accL1); PUTACC(dp, 32, accL2); PUTACC(dp, 48, accL3);
    }
    __syncthreads();
    if (w == 0) {
        const float* dp = xredb + lane * 68;
        ADDACC(dp, 0, accL0); ADDACC(dp, 16, accL1); ADDACC(dp, 32, accL2); ADDACC(dp, 48, accL3);
        #pragma unroll
        for (int n = 0; n < 4; n++) {
            union { f32x16 v; f32x4 q[4]; } t;
            t.v = (n == 0) ? accL0 : (n == 1) ? accL1 : (n == 2) ? accL2 : accL3;
            int col = h * 128 + n * 32 + l31;
            float bv = bias[col];
            #pragma unroll
            for (int r = 0; r < 16; r++) {
                int row = i0 + (r & 3) + 8 * (r >> 2) + 4 * half;
                out[(size_t)row * 1024 + col] = t.v[r] + bv;
            }
        }
    }

    // pass H
    __syncthreads();
    if (w >= 2) {
        float* dp = xredb + (w - 2) * 4352 + lane * 68;
        PUTACC(dp, 0, accH0); PUTACC(dp, 16, accH1); PUTACC(dp, 32, accH2); PUTACC(dp, 48, accH3);
    }
    __syncthreads();
    if (w < 2) {
        const float* dp = xredb + w * 4352 + lane * 68;
        ADDACC(dp, 0, accH0); ADDACC(dp, 16, accH1); ADDACC(dp, 32, accH2); ADDACC(dp, 48, accH3);
    }
    __syncthreads();
    if (w == 1) {
        float* dp = xredb + lane * 68;
        PUTACC(dp, 0, accH0); PUTACC(dp, 16, accH1); PUTACC(dp, 32, accH2); PUTACC(dp, 48, accH3);
    }
    __syncthreads();
    if (w == 0) {
        const float* dp = xredb + lane * 68;
        ADDACC(dp, 0, accH0); ADDACC(dp, 16, accH1); ADDACC(dp, 32, accH2); ADDACC(dp, 48, accH3);
        #pragma unroll
        for (int n = 0; n < 4; n++) {
            union { f32x16 v; f32x4 q[4]; } t;
            t.v = (n == 0) ? accH0 : (n == 1) ? accH1 : (n == 2) ? accH2 : accH3;
            int col = h * 128 + n * 32 + l31;
            float bv = bias[col];
            #pragma unroll
            for (int r = 0; r < 16; r++) {
                int row = i0 + 32 + (r & 3) + 8 * (r >> 2) + 4 * half;
                out[(size_t)row * 1024 + col] = t.v[r] + bv;
            }
        }
    }
}

extern "C" void kernel_launch(void* const* d_in, const int* in_sizes, int n_in,
                              void* d_out, int out_size, void* d_ws, size_t ws_size,
                              hipStream_t stream) {
    (void)in_sizes; (void)n_in; (void)out_size; (void)ws_size;
    const float* x     = (const float*)d_in[0];
    const int*   graph = (const int*)d_in[1];
    const float* W     = (const float*)d_in[2];
    const float* wi    = (const float*)d_in[3];
    const float* wj    = (const float*)d_in[4];
    const float* Wr    = (const float*)d_in[5];
    const float* bias  = (const float*)d_in[6];
    float* out = (float*)d_out;

    char* ws = (char*)d_ws;
    unsigned int* maskJ = (unsigned int*)ws;              // 2 MB  [128 jw][4096 i]
    f16* hbT2  = (f16*)(ws + (2u << 20));                 // 8 MB  [8][(j>>4)*128+f][j&15]
    f16* Wht2  = (f16*)(ws + (10u << 20));                // 1 MB  swizzled
    f16* Wrt2  = (f16*)(ws + (11u << 20));                // 1 MB  swizzled
    f16* xh2   = (f16*)(ws + (12u << 20));                // 4 MB  [32][4096][16] swizzled
    float* a2    = (float*)(ws + (16u << 20));            // 128 KB
    float* b2    = a2 + 8 * 4096;                         // 128 KB
    unsigned int* M2e = (unsigned int*)(b2 + 8 * 4096);   // 32 B

    hipLaunchKernelGGL(k_a, dim3(1536), dim3(256), 0, stream, x, xh2, W, Wht2, Wr, Wrt2, M2e);
    hipLaunchKernelGGL(k_b, dim3(3072), dim3(256), 0, stream, xh2, Wht2, hbT2,
                       wi, wj, a2, b2, M2e, graph, maskJ);
    hipLaunchKernelGGL(k_main, dim3(512), dim3(256), 0, stream, xh2, hbT2, Wrt2, maskJ,
                       a2, b2, M2e, bias, out);
}

// Round 6
// 180.062 us; speedup vs baseline: 1.3271x; 1.0169x over previous
//
#include <hip/hip_runtime.h>
#include <hip/hip_fp16.h>

typedef _Float16 f16;
typedef _Float16 f16x8 __attribute__((ext_vector_type(8)));
typedef _Float16 f16x2v __attribute__((ext_vector_type(2)));
typedef __fp16 h16x2 __attribute__((ext_vector_type(2)));
typedef float f32x4 __attribute__((ext_vector_type(4)));
typedef float f32x16 __attribute__((ext_vector_type(16)));

#define LOG2E 1.4426950408889634f
#define NSL 0.2f

// ---------------- Kernel A: xcvt + swizzled weight transposes + M2e init ----------------
__global__ __launch_bounds__(256) void k_a(const float* __restrict__ x,
                                           f16* __restrict__ xh2,
                                           const float* __restrict__ W,
                                           f16* __restrict__ Wht2,
                                           const float* __restrict__ Wr,
                                           f16* __restrict__ Wrt2,
                                           unsigned int* __restrict__ M2e) {
    __shared__ float tile[32][33];
    int bx = blockIdx.x;
    int tid = threadIdx.x;
    if (bx == 0 && tid < 8) M2e[tid] = 0x007FFFFFu;  // enc(-inf)
    if (bx < 512) {
        int id = bx * 256 + tid;   // 131072
        int row = id & 4095, kt = id >> 12;
        const float4* xs = (const float4*)(x + (size_t)row * 512 + kt * 16);
        float4 u0 = xs[0], u1 = xs[1], u2 = xs[2], u3 = xs[3];
        union { int4 a[2]; h16x2 p[8]; } px;
        px.p[0] = __builtin_amdgcn_cvt_pkrtz(u0.x, u0.y);
        px.p[1] = __builtin_amdgcn_cvt_pkrtz(u0.z, u0.w);
        px.p[2] = __builtin_amdgcn_cvt_pkrtz(u1.x, u1.y);
        px.p[3] = __builtin_amdgcn_cvt_pkrtz(u1.z, u1.w);
        px.p[4] = __builtin_amdgcn_cvt_pkrtz(u2.x, u2.y);
        px.p[5] = __builtin_amdgcn_cvt_pkrtz(u2.z, u2.w);
        px.p[6] = __builtin_amdgcn_cvt_pkrtz(u3.x, u3.y);
        px.p[7] = __builtin_amdgcn_cvt_pkrtz(u3.z, u3.w);
        int4* d = (int4*)(xh2 + ((size_t)kt * 4096 + row) * 16);
        d[0] = px.a[0]; d[1] = px.a[1];
    } else {
        const float* in; f16* out; int C, S, bxx, byy;
        if (bx < 1024) { int id = bx - 512;  in = W;  out = Wht2; C = 128;  S = 128;  bxx = id & 3;  byy = id >> 2; }
        else           { int id = bx - 1024; in = Wr; out = Wrt2; C = 1024; S = 1024; bxx = id & 31; byy = id >> 5; }
        int tx = tid & 31, ty = tid >> 5;
        int c0 = bxx * 32, r0 = byy * 32;
        for (int rr = ty; rr < 32; rr += 8)
            tile[rr][tx] = in[(r0 + rr) * C + c0 + tx];
        __syncthreads();
        for (int rr = ty; rr < 32; rr += 8) {
            int m = r0 + tx, f = c0 + rr;
            out[(size_t)((m >> 4) * S + f) * 16 + (m & 15)] = (f16)tile[tx][rr];
        }
    }
}

// ---------------- Kernel B (fused): gemm_h (blocks 0..1023) + graph bitmask (1024..3071) ----------------
// Mask build: ballot-free, 32 independent dword loads per thread -> deep MLP, HBM-BW-bound.
__global__ __launch_bounds__(256, 4) void k_b(const f16* __restrict__ xh2,
                                              const f16* __restrict__ Wht2,
                                              f16* __restrict__ hbT2,
                                              const float* __restrict__ wi,
                                              const float* __restrict__ wj,
                                              float* __restrict__ a2,
                                              float* __restrict__ b2,
                                              unsigned int* __restrict__ M2e,
                                              const int* __restrict__ graph,
                                              unsigned int* __restrict__ maskJ) {
    __shared__ float swi[128], swj[128];
    __shared__ float pwa[4][32], pwb[4][32];
    int bx = blockIdx.x;
    int tid = threadIdx.x;
    int w = tid >> 6, lane = tid & 63;

    if (bx >= 1024) {
        // ---- mask part: one thread per output word, 32-deep independent loads ----
        int e = (bx - 1024) * 256 + tid;       // 0..524287 = jw*4096 + i
        int jw = e >> 12, ii = e & 4095;
        const int* gp = graph + (size_t)(jw << 5) * 4096 + ii;
        int gv[32];
        #pragma unroll
        for (int k = 0; k < 32; k++) gv[k] = gp[(size_t)k * 4096];
        unsigned word = 0;
        #pragma unroll
        for (int k = 0; k < 32; k++) word |= (gv[k] > 0) ? (1u << k) : 0u;
        maskJ[e] = word;
        return;
    }

    // ---- gemm part ----
    int h = bx & 7, jb = bx >> 3;        // 128 j-tiles of 32
    int j0 = jb * 32;
    int ln = lane & 15, q = lane >> 4;
    if (tid < 128) { swi[tid] = wi[h * 128 + tid]; swj[tid] = wj[h * 128 + tid]; }
    __syncthreads();

    int ko = (q & 1) * 8;
    const f16* pa = Wht2 + ((size_t)(h * 512) * 8 + (size_t)(q >> 1) * 128 + w * 32 + ln) * 16 + ko;
    const f16* pb = xh2 + ((size_t)(q >> 1) * 4096 + j0 + ln) * 16 + ko;

    f32x4 acc00 = {}, acc01 = {}, acc10 = {}, acc11 = {};

    f16x8 ra0 = *(const f16x8*)(pa);
    f16x8 ra1 = *(const f16x8*)(pa + 256);
    f16x8 rb0 = *(const f16x8*)(pb);
    f16x8 rb1 = *(const f16x8*)(pb + 256);

    for (int kk = 0; kk < 8; kk++) {
        f16x8 sa0 = *(const f16x8*)(pa + 4096);
        f16x8 sa1 = *(const f16x8*)(pa + 4096 + 256);
        f16x8 sb0 = *(const f16x8*)(pb + 131072);
        f16x8 sb1 = *(const f16x8*)(pb + 131072 + 256);
        acc00 = __builtin_amdgcn_mfma_f32_16x16x32_f16(ra0, rb0, acc00, 0, 0, 0);
        acc01 = __builtin_amdgcn_mfma_f32_16x16x32_f16(ra0, rb1, acc01, 0, 0, 0);
        acc10 = __builtin_amdgcn_mfma_f32_16x16x32_f16(ra1, rb0, acc10, 0, 0, 0);
        acc11 = __builtin_amdgcn_mfma_f32_16x16x32_f16(ra1, rb1, acc11, 0, 0, 0);
        pa += 8192; pb += 262144;
        ra0 = *(const f16x8*)(pa);
        ra1 = *(const f16x8*)(pa + 256);
        rb0 = *(const f16x8*)(pb);
        rb1 = *(const f16x8*)(pb + 256);
        acc00 = __builtin_amdgcn_mfma_f32_16x16x32_f16(sa0, sb0, acc00, 0, 0, 0);
        acc01 = __builtin_amdgcn_mfma_f32_16x16x32_f16(sa0, sb1, acc01, 0, 0, 0);
        acc10 = __builtin_amdgcn_mfma_f32_16x16x32_f16(sa1, sb0, acc10, 0, 0, 0);
        acc11 = __builtin_amdgcn_mfma_f32_16x16x32_f16(sa1, sb1, acc11, 0, 0, 0);
    }

    size_t hb = (size_t)h * 524288 + (size_t)(j0 >> 4) * 2048;
    #pragma unroll
    for (int r = 0; r < 4; r++) {
        int f0 = w * 32 + q * 4 + r;
        hbT2[hb + f0 * 16 + ln]                 = (f16)acc00[r];
        hbT2[hb + 2048 + f0 * 16 + ln]          = (f16)acc01[r];
        hbT2[hb + (f0 + 16) * 16 + ln]          = (f16)acc10[r];
        hbT2[hb + 2048 + (f0 + 16) * 16 + ln]   = (f16)acc11[r];
    }

    float pa0 = 0.f, pb0 = 0.f, pa1 = 0.f, pb1 = 0.f;
    #pragma unroll
    for (int r = 0; r < 4; r++) {
        int f0 = w * 32 + q * 4 + r;
        float w0 = swi[f0], jv0 = swj[f0];
        float w1 = swi[f0 + 16], jv1 = swj[f0 + 16];
        pa0 += acc00[r] * w0 + acc10[r] * w1;
        pb0 += acc00[r] * jv0 + acc10[r] * jv1;
        pa1 += acc01[r] * w0 + acc11[r] * w1;
        pb1 += acc01[r] * jv0 + acc11[r] * jv1;
    }
    pa0 += __shfl_xor(pa0, 16); pa0 += __shfl_xor(pa0, 32);
    pb0 += __shfl_xor(pb0, 16); pb0 += __shfl_xor(pb0, 32);
    pa1 += __shfl_xor(pa1, 16); pa1 += __shfl_xor(pa1, 32);
    pb1 += __shfl_xor(pb1, 16); pb1 += __shfl_xor(pb1, 32);
    if (lane < 16) {
        pwa[w][ln] = pa0;      pwb[w][ln] = pb0;
        pwa[w][16 + ln] = pa1; pwb[w][16 + ln] = pb1;
    }
    __syncthreads();
    if (tid < 32) {
        int jj = tid;
        float pav = (pwa[0][jj] + pwa[1][jj]) + (pwa[2][jj] + pwa[3][jj]);
        float pbv = (pwb[0][jj] + pwb[1][jj]) + (pwb[2][jj] + pwb[3][jj]);
        a2[h * 4096 + j0 + jj] = pav * LOG2E;
        float bb = pbv * LOG2E;
        b2[h * 4096 + j0 + jj] = bb;
        float m = bb;
        m = fmaxf(m, __shfl_xor(m, 1, 32));
        m = fmaxf(m, __shfl_xor(m, 2, 32));
        m = fmaxf(m, __shfl_xor(m, 4, 32));
        m = fmaxf(m, __shfl_xor(m, 8, 32));
        m = fmaxf(m, __shfl_xor(m, 16, 32));
        if (jj == 0) {
            unsigned u = __float_as_uint(m);
            unsigned enc = (u & 0x80000000u) ? ~u : (u | 0x80000000u);
            atomicMax(&M2e[h], enc);
        }
    }
}

// ---------------- Kernel 6 helpers ----------------
// PGEN2: build one 16-j attention fragment for row set (A1,A2 = per-row factors),
// accumulating the row denominator into DS.
#define PGEN2(af, m8, qv, qw, A1, A2, DS)                                            \
    {                                                                                \
        union { int4 i4; unsigned u[4]; } uv, uw;                                    \
        uv.i4 = (qv); uw.i4 = (qw);                                                  \
        f16x2v dl = {(_Float16)0, (_Float16)0};                                      \
        _Pragma("unroll")                                                            \
        for (int p = 0; p < 4; p++) {                                                \
            union { unsigned u; f16x2v v; } b1, b2x, mm;                             \
            b1.u = uv.u[p]; b2x.u = uw.u[p];                                         \
            f16x2v pr1 = (A1) * b1.v;                                                \
            f16x2v pr2 = (A2) * b2x.v;                                               \
            mm.v = __builtin_elementwise_max(pr1, pr2);                              \
            int mlo = -(int)(((m8) >> (2 * p)) & 1u);                                \
            int mhi = -(int)(((m8) >> (2 * p + 1)) & 1u);                            \
            unsigned comb = ((unsigned)mlo & 0xFFFFu) | ((unsigned)mhi & 0xFFFF0000u);\
            mm.u &= comb;                                                            \
            af.u[p] = mm.u;                                                          \
            dl += mm.v;                                                              \
        }                                                                            \
        DS += (float)dl.x + (float)dl.y;                                             \
    }

#define PUTACC(dp, off, accv)                                                    \
    {                                                                            \
        union { f32x16 v; f32x4 q[4]; } t; t.v = (accv);                         \
        *(f32x4*)((dp) + (off))      = t.q[0];                                   \
        *(f32x4*)((dp) + (off) + 4)  = t.q[1];                                   \
        *(f32x4*)((dp) + (off) + 8)  = t.q[2];                                   \
        *(f32x4*)((dp) + (off) + 12) = t.q[3];                                   \
    }

#define ADDACC(dp, off, accv)                                                    \
    {                                                                            \
        union { f32x16 v; f32x4 q[4]; } t; t.v = (accv);                         \
        t.q[0] += *(const f32x4*)((dp) + (off));                                 \
        t.q[1] += *(const f32x4*)((dp) + (off) + 4);                             \
        t.q[2] += *(const f32x4*)((dp) + (off) + 8);                             \
        t.q[3] += *(const f32x4*)((dp) + (off) + 12);                            \
        (accv) = t.v;                                                            \
    }

// ---------------- Kernel 6: main — 64-row i-tiles; mask read DIRECT from global (L2)
// with 1-tp prefetch (LDS staging removed: each word consumed once); s_setprio around
// MFMA clusters; 2 waves/SIMD ----------------
__global__ __launch_bounds__(256, 2) void k_main(const f16* __restrict__ xh2,
                                                 const f16* __restrict__ hbT2,
                                                 const f16* __restrict__ Wrt2,
                                                 const unsigned int* __restrict__ maskJ,
                                                 const float* __restrict__ a2,
                                                 const float* __restrict__ b2,
                                                 const unsigned int* __restrict__ M2e,
                                                 const float* __restrict__ bias,
                                                 float* __restrict__ out) {
    // loop phase: [0,8192) Bv | [8192,16384) Bw  (+16B tail overread pad inside region)
    // post-loop:  [0,34816) xred (aliases Bv/Bw, separated by __syncthreads)
    __shared__ char smem[35328];
    __shared__ float dred[256];           // [wave][64 rows]

    unsigned int* bvlds = (unsigned int*)smem;
    unsigned int* bwlds = (unsigned int*)(smem + 8192);

    int bx = blockIdx.x;
    int h = bx & 7, it = bx >> 3;         // 64 i-tiles of 64 rows
    int i0 = it * 64;
    int tid = threadIdx.x;
    int w = tid >> 6, lane = tid & 63;
    int l31 = lane & 31, half = lane >> 5;
    int i = i0 + l31;

    unsigned enc = M2e[h];
    unsigned um = (enc & 0x80000000u) ? (enc & 0x7FFFFFFFu) : ~enc;
    float M2 = __uint_as_float(um);

    // ---- build Bv/Bw tables in LDS from b2 ----
    {
        const float2* bsrc = (const float2*)(b2 + h * 4096);
        #pragma unroll
        for (int c = 0; c < 8; c++) {
            int p = tid + c * 256;                 // 2048 j-pairs
            float2 tb = bsrc[p];
            float t0 = tb.x - M2, t1 = tb.y - M2;
            union { h16x2 pp; unsigned ii; } k1, k2;
            k1.pp = __builtin_amdgcn_cvt_pkrtz(exp2f(t0), exp2f(t1));
            k2.pp = __builtin_amdgcn_cvt_pkrtz(exp2f(NSL * t0), exp2f(NSL * t1));
            bvlds[p] = k1.ii;
            bwlds[p] = k2.ii;
        }
    }

    // ---- per-row A factors (two row sets: i0+l31 and i0+32+l31) ----
    float avL = a2[h * 4096 + i];
    float avH = a2[h * 4096 + i + 32];
    float uuL = avL + M2, uuH = avH + M2;
    float mvL = fmaxf(uuL, NSL * uuL);
    float mvH = fmaxf(uuH, NSL * uuH);
    union { h16x2 pp; f16x2v v; } apL, apH;
    apL.pp = __builtin_amdgcn_cvt_pkrtz(exp2f(uuL - mvL), exp2f(NSL * uuL - mvL));
    apH.pp = __builtin_amdgcn_cvt_pkrtz(exp2f(uuH - mvH), exp2f(NSL * uuH - mvH));
    f16x2v ApL1 = {apL.v.x, apL.v.x};
    f16x2v ApL2 = {apL.v.y, apL.v.y};
    f16x2v ApH1 = {apH.v.x, apH.v.x};
    f16x2v ApH2 = {apH.v.y, apH.v.y};

    f32x16 accL0 = {}, accL1 = {}, accL2 = {}, accL3 = {};
    f32x16 accH0 = {}, accH1 = {}, accH2 = {}, accH3 = {};
    float dsumL = 0.f, dsumH = 0.f;

    int J0 = w * 1024;
    const f16* bb = hbT2 + (size_t)h * 524288 + ((size_t)(J0 >> 4) * 128 + l31) * 16 + half * 8;
    const unsigned int* bpv = bvlds + (J0 >> 1) + half * 4;
    const unsigned int* bpw = bwlds + (J0 >> 1) + half * 4;
    // mask: word for row i, tile-pair tp is maskJ[((J0>>5)+tp)*4096 + i]; H row at +32 dwords (offset 128B)
    const unsigned int* mp = maskJ + (size_t)(J0 >> 5) * 4096 + i;

    int sh0 = half << 3;
    int sh1 = 16 + (half << 3);

    __syncthreads();

    // prologue
    f16x8 fa0 = *(const f16x8*)(bb);
    f16x8 fa1 = *(const f16x8*)(bb + 512);
    f16x8 fa2 = *(const f16x8*)(bb + 1024);
    f16x8 fa3 = *(const f16x8*)(bb + 1536);
    int4 qv0 = ((const int4*)(bpv))[0];
    int4 qw0 = ((const int4*)(bpw))[0];
    unsigned mwcL = mp[0];
    unsigned mwcH = mp[32];
    mp += 4096;

    for (int tp = 0; tp < 32; tp++) {
        int t0 = tp * 2;
        const f16* s1 = bb + (size_t)(t0 + 1) * 2048;
        f16x8 fb0 = *(const f16x8*)(s1);
        f16x8 fb1 = *(const f16x8*)(s1 + 512);
        f16x8 fb2 = *(const f16x8*)(s1 + 1024);
        f16x8 fb3 = *(const f16x8*)(s1 + 1536);
        int4 qv1 = *(const int4*)(bpv + (t0 + 1) * 8);
        int4 qw1 = *(const int4*)(bpw + (t0 + 1) * 8);
        unsigned mwnL = mp[0];      // prefetch next tile-pair's mask words (L2, 1-tp distance)
        unsigned mwnH = mp[32];
        mp += 4096;

        {
            union { f16x8 v; unsigned u[4]; } af;
            PGEN2(af, mwcL >> sh0, qv0, qw0, ApL1, ApL2, dsumL);
            __builtin_amdgcn_s_setprio(1);
            accL0 = __builtin_amdgcn_mfma_f32_32x32x16_f16(af.v, fa0, accL0, 0, 0, 0);
            accL1 = __builtin_amdgcn_mfma_f32_32x32x16_f16(af.v, fa1, accL1, 0, 0, 0);
            accL2 = __builtin_amdgcn_mfma_f32_32x32x16_f16(af.v, fa2, accL2, 0, 0, 0);
            accL3 = __builtin_amdgcn_mfma_f32_32x32x16_f16(af.v, fa3, accL3, 0, 0, 0);
            __builtin_amdgcn_s_setprio(0);
        }
        {
            union { f16x8 v; unsigned u[4]; } af;
            PGEN2(af, mwcH >> sh0, qv0, qw0, ApH1, ApH2, dsumH);
            __builtin_amdgcn_s_setprio(1);
            accH0 = __builtin_amdgcn_mfma_f32_32x32x16_f16(af.v, fa0, accH0, 0, 0, 0);
            accH1 = __builtin_amdgcn_mfma_f32_32x32x16_f16(af.v, fa1, accH1, 0, 0, 0);
            accH2 = __builtin_amdgcn_mfma_f32_32x32x16_f16(af.v, fa2, accH2, 0, 0, 0);
            accH3 = __builtin_amdgcn_mfma_f32_32x32x16_f16(af.v, fa3, accH3, 0, 0, 0);
            __builtin_amdgcn_s_setprio(0);
        }

        const f16* s2 = bb + (size_t)(t0 + 2) * 2048;
        fa0 = *(const f16x8*)(s2);
        fa1 = *(const f16x8*)(s2 + 512);
        fa2 = *(const f16x8*)(s2 + 1024);
        fa3 = *(const f16x8*)(s2 + 1536);
        qv0 = *(const int4*)(bpv + (t0 + 2) * 8);
        qw0 = *(const int4*)(bpw + (t0 + 2) * 8);

        {
            union { f16x8 v; unsigned u[4]; } af;
            PGEN2(af, mwcL >> sh1, qv1, qw1, ApL1, ApL2, dsumL);
            __builtin_amdgcn_s_setprio(1);
            accL0 = __builtin_amdgcn_mfma_f32_32x32x16_f16(af.v, fb0, accL0, 0, 0, 0);
            accL1 = __builtin_amdgcn_mfma_f32_32x32x16_f16(af.v, fb1, accL1, 0, 0, 0);
            accL2 = __builtin_amdgcn_mfma_f32_32x32x16_f16(af.v, fb2, accL2, 0, 0, 0);
            accL3 = __builtin_amdgcn_mfma_f32_32x32x16_f16(af.v, fb3, accL3, 0, 0, 0);
            __builtin_amdgcn_s_setprio(0);
        }
        {
            union { f16x8 v; unsigned u[4]; } af;
            PGEN2(af, mwcH >> sh1, qv1, qw1, ApH1, ApH2, dsumH);
            __builtin_amdgcn_s_setprio(1);
            accH0 = __builtin_amdgcn_mfma_f32_32x32x16_f16(af.v, fb0, accH0, 0, 0, 0);
            accH1 = __builtin_amdgcn_mfma_f32_32x32x16_f16(af.v, fb1, accH1, 0, 0, 0);
            accH2 = __builtin_amdgcn_mfma_f32_32x32x16_f16(af.v, fb2, accH2, 0, 0, 0);
            accH3 = __builtin_amdgcn_mfma_f32_32x32x16_f16(af.v, fb3, accH3, 0, 0, 0);
            __builtin_amdgcn_s_setprio(0);
        }
        mwcL = mwnL;
        mwcH = mwnH;
    }

    // ---- denominator ----
    dsumL += __shfl(dsumL, lane ^ 32);
    dsumH += __shfl(dsumH, lane ^ 32);
    if (lane < 32) {
        dred[w * 64 + l31] = dsumL;
        dred[w * 64 + 32 + l31] = dsumH;
    }
    __syncthreads();
    {
        #pragma unroll
        for (int r = 0; r < 16; r++) {
            int row = (r & 3) + 8 * (r >> 2) + 4 * half;
            float sL = dred[row] + dred[64 + row] + dred[128 + row] + dred[192 + row];
            float sH = dred[32 + row] + dred[96 + row] + dred[160 + row] + dred[224 + row];
            float invL = 1.0f / sL;
            float invH = 1.0f / sH;
            accL0[r] *= invL; accL1[r] *= invL; accL2[r] *= invL; accL3[r] *= invL;
            accH0[r] *= invH; accH1[r] *= invH; accH2[r] *= invH; accH3[r] *= invH;
        }
    }

    // ---- residual (per-wave partial over K/4, summed in cross-wave reduction) ----
    {
        #pragma unroll
        for (int kt = 0; kt < 8; kt++) {
            int ktt = w * 8 + kt;
            f16x8 axL = *(const f16x8*)(xh2 + ((size_t)ktt * 4096 + i) * 16 + half * 8);
            f16x8 axH = *(const f16x8*)(xh2 + ((size_t)ktt * 4096 + i + 32) * 16 + half * 8);
            const f16* wb = Wrt2 + ((size_t)ktt * 1024 + h * 128 + l31) * 16 + half * 8;
            f16x8 wb0 = *(const f16x8*)(wb);
            f16x8 wb1 = *(const f16x8*)(wb + 512);
            f16x8 wb2 = *(const f16x8*)(wb + 1024);
            f16x8 wb3 = *(const f16x8*)(wb + 1536);
            accL0 = __builtin_amdgcn_mfma_f32_32x32x16_f16(axL, wb0, accL0, 0, 0, 0);
            accL1 = __builtin_amdgcn_mfma_f32_32x32x16_f16(axL, wb1, accL1, 0, 0, 0);
            accL2 = __builtin_amdgcn_mfma_f32_32x32x16_f16(axL, wb2, accL2, 0, 0, 0);
            accL3 = __builtin_amdgcn_mfma_f32_32x32x16_f16(axL, wb3, accL3, 0, 0, 0);
            accH0 = __builtin_amdgcn_mfma_f32_32x32x16_f16(axH, wb0, accH0, 0, 0, 0);
            accH1 = __builtin_amdgcn_mfma_f32_32x32x16_f16(axH, wb1, accH1, 0, 0, 0);
            accH2 = __builtin_amdgcn_mfma_f32_32x32x16_f16(axH, wb2, accH2, 0, 0, 0);
            accH3 = __builtin_amdgcn_mfma_f32_32x32x16_f16(axH, wb3, accH3, 0, 0, 0);
        }
    }

    // ---- cross-wave O reduction: pass L (rows i0..i0+31), then pass H (+32) ----
    float* xredb = (float*)smem;

    // pass L
    __syncthreads();
    if (w >= 2) {
        float* dp = xredb + (w - 2) * 4352 + lane * 68;
        PUTACC(dp, 0, accL0); PUTACC(dp, 16, accL1); PUTACC(dp, 32, accL2); PUTACC(dp, 48, accL3);
    }
    __syncthreads();
    if (w < 2) {
        const float* dp = xredb + w * 4352 + lane * 68;
        ADDACC(dp, 0, accL0); ADDACC(dp, 16, accL1); ADDACC(dp, 32, accL2); ADDACC(dp, 48, accL3);
    }
    __syncthreads();
    if (w == 1) {
        float* dp = xredb + lane * 68;
        PUTACC(dp, 0, accL0); PUTACC(dp, 16, accL1); PUTACC(dp, 32, accL2); PUTACC(dp, 48, accL3);
    }
    __syncthreads();
    if (w == 0) {
        const float* dp = xredb + lane * 68;
        ADDACC(dp, 0, accL0); ADDACC(dp, 16, accL1); ADDACC(dp, 32, accL2); ADDACC(dp, 48, accL3);
        #pragma unroll
        for (int n = 0; n < 4; n++) {
            union { f32x16 v; f32x4 q[4]; } t;
            t.v = (n == 0) ? accL0 : (n == 1) ? accL1 : (n == 2) ? accL2 : accL3;
            int col = h * 128 + n * 32 + l31;
            float bv = bias[col];
            #pragma unroll
            for (int r = 0; r < 16; r++) {
                int row = i0 + (r & 3) + 8 * (r >> 2) + 4 * half;
                out[(size_t)row * 1024 + col] = t.v[r] + bv;
            }
        }
    }

    // pass H
    __syncthreads();
    if (w >= 2) {
        float* dp = xredb + (w - 2) * 4352 + lane * 68;
        PUTACC(dp, 0, accH0); PUTACC(dp, 16, accH1); PUTACC(dp, 32, accH2); PUTACC(dp, 48, accH3);
    }
    __syncthreads();
    if (w < 2) {
        const float* dp = xredb + w * 4352 + lane * 68;
        ADDACC(dp, 0, accH0); ADDACC(dp, 16, accH1); ADDACC(dp, 32, accH2); ADDACC(dp, 48, accH3);
    }
    __syncthreads();
    if (w == 1) {
        float* dp = xredb + lane * 68;
        PUTACC(dp, 0, accH0); PUTACC(dp, 16, accH1); PUTACC(dp, 32, accH2); PUTACC(dp, 48, accH3);
    }
    __syncthreads();
    if (w == 0) {
        const float* dp = xredb + lane * 68;
        ADDACC(dp, 0, accH0); ADDACC(dp, 16, accH1); ADDACC(dp, 32, accH2); ADDACC(dp, 48, accH3);
        #pragma unroll
        for (int n = 0; n < 4; n++) {
            union { f32x16 v; f32x4 q[4]; } t;
            t.v = (n == 0) ? accH0 : (n == 1) ? accH1 : (n == 2) ? accH2 : accH3;
            int col = h * 128 + n * 32 + l31;
            float bv = bias[col];
            #pragma unroll
            for (int r = 0; r < 16; r++) {
                int row = i0 + 32 + (r & 3) + 8 * (r >> 2) + 4 * half;
                out[(size_t)row * 1024 + col] = t.v[r] + bv;
            }
        }
    }
}

extern "C" void kernel_launch(void* const* d_in, const int* in_sizes, int n_in,
                              void* d_out, int out_size, void* d_ws, size_t ws_size,
                              hipStream_t stream) {
    (void)in_sizes; (void)n_in; (void)out_size; (void)ws_size;
    const float* x     = (const float*)d_in[0];
    const int*   graph = (const int*)d_in[1];
    const float* W     = (const float*)d_in[2];
    const float* wi    = (const float*)d_in[3];
    const float* wj    = (const float*)d_in[4];
    const float* Wr    = (const float*)d_in[5];
    const float* bias  = (const float*)d_in[6];
    float* out = (float*)d_out;

    char* ws = (char*)d_ws;
    unsigned int* maskJ = (unsigned int*)ws;              // 2 MB  [128 jw][4096 i]
    f16* hbT2  = (f16*)(ws + (2u << 20));                 // 8 MB  [8][(j>>4)*128+f][j&15]
    f16* Wht2  = (f16*)(ws + (10u << 20));                // 1 MB  swizzled
    f16* Wrt2  = (f16*)(ws + (11u << 20));                // 1 MB  swizzled
    f16* xh2   = (f16*)(ws + (12u << 20));                // 4 MB  [32][4096][16] swizzled
    float* a2    = (float*)(ws + (16u << 20));            // 128 KB
    float* b2    = a2 + 8 * 4096;                         // 128 KB
    unsigned int* M2e = (unsigned int*)(b2 + 8 * 4096);   // 32 B

    hipLaunchKernelGGL(k_a, dim3(1536), dim3(256), 0, stream, x, xh2, W, Wht2, Wr, Wrt2, M2e);
    hipLaunchKernelGGL(k_b, dim3(3072), dim3(256), 0, stream, xh2, Wht2, hbT2,
                       wi, wj, a2, b2, M2e, graph, maskJ);
    hipLaunchKernelGGL(k_main, dim3(512), dim3(256), 0, stream, xh2, hbT2, Wrt2, maskJ,
                       a2, b2, M2e, bias, out);
}